// Round 1
// baseline (30571.384 us; speedup 1.0000x reference)
//
#include <hip/hip_runtime.h>
#include <math.h>

#define Bb 128
#define Nn 100
#define Ee 512
#define Hh 8
#define DHd 64
#define FFf 2048
#define Ll 6
#define STEPS 150

typedef _Float16 h8 __attribute__((ext_vector_type(8)));
typedef _Float16 h4 __attribute__((ext_vector_type(4)));
typedef float f4 __attribute__((ext_vector_type(4)));

// ---------------------------------------------------------------------------
// Split-f16 MFMA GEMM.  C[M,N] = A[M,K] @ B[K,N] computed as
// Ah*Bh + Ah*Bl + Al*Bh with f16 hi/lo planes (pre-split inputs).
// A planes: [M][K] f16.  B planes: pre-transposed [N][K] f16.
// Tile 128x128, BK=32, 4 waves (2x2), each wave 4x4 frags of 16x16x32.
// OUTF32: fp32 (+bias,+relu).  else: write f16 hi/lo planes (+bias,+relu).
// SPLITK: blockIdx.z picks K-chunk kc, partial to C + z*Mtot*ldc, no bias.
// ---------------------------------------------------------------------------
template<bool RELU, bool BIAS, bool OUTF32, bool SPLITK>
__global__ __launch_bounds__(256) void mgemm_k(
    const _Float16* __restrict__ Ah, const _Float16* __restrict__ Al, int lda,
    const _Float16* __restrict__ Bh, const _Float16* __restrict__ Bl, int ldb,
    float* __restrict__ C, _Float16* __restrict__ Ch, _Float16* __restrict__ Cl,
    int ldc, const float* __restrict__ bias, int K, int kc, int Mtot)
{
  __shared__ _Float16 sm[4 * 5120];            // 4 planes of 128 x (32+8pad)
  _Float16* sAh = sm;
  _Float16* sAl = sm + 5120;
  _Float16* sBh = sm + 10240;
  _Float16* sBl = sm + 15360;
  const int tid = threadIdx.x;
  const int m0 = blockIdx.y * 128, n0 = blockIdx.x * 128;
  const int k0 = SPLITK ? blockIdx.z * kc : 0;
  const int kEnd = SPLITK ? k0 + kc : K;
  const int lane = tid & 63, wave = tid >> 6;
  const int wm = wave >> 1, wn = wave & 1;
  const int m16 = lane & 15, kg = lane >> 4;
  f4 acc[4][4];
#pragma unroll
  for (int i = 0; i < 4; ++i)
#pragma unroll
    for (int j = 0; j < 4; ++j) acc[i][j] = (f4)0.f;

  for (int kt = k0; kt < kEnd; kt += 32) {
#pragma unroll
    for (int it = 0; it < 2; ++it) {
      int idx = tid + it * 256;                // 512 (row,g) slots
      int row = idx >> 2, g = idx & 3;
      int lo_ = row * 40 + g * 8;
      size_t ga = (size_t)(m0 + row) * lda + kt + g * 8;
      size_t gb = (size_t)(n0 + row) * ldb + kt + g * 8;
      *(h8*)(sAh + lo_) = *(const h8*)(Ah + ga);
      *(h8*)(sAl + lo_) = *(const h8*)(Al + ga);
      *(h8*)(sBh + lo_) = *(const h8*)(Bh + gb);
      *(h8*)(sBl + lo_) = *(const h8*)(Bl + gb);
    }
    __syncthreads();
    h8 a_h[4], a_l[4], b_h[4], b_l[4];
#pragma unroll
    for (int i = 0; i < 4; ++i) {
      int ro = (wm * 64 + i * 16 + m16) * 40 + kg * 8;
      int co = (wn * 64 + i * 16 + m16) * 40 + kg * 8;
      a_h[i] = *(const h8*)(sAh + ro);
      a_l[i] = *(const h8*)(sAl + ro);
      b_h[i] = *(const h8*)(sBh + co);
      b_l[i] = *(const h8*)(sBl + co);
    }
#pragma unroll
    for (int i = 0; i < 4; ++i)
#pragma unroll
      for (int j = 0; j < 4; ++j) {
        acc[i][j] = __builtin_amdgcn_mfma_f32_16x16x32_f16(a_h[i], b_h[j], acc[i][j], 0, 0, 0);
        acc[i][j] = __builtin_amdgcn_mfma_f32_16x16x32_f16(a_h[i], b_l[j], acc[i][j], 0, 0, 0);
        acc[i][j] = __builtin_amdgcn_mfma_f32_16x16x32_f16(a_l[i], b_h[j], acc[i][j], 0, 0, 0);
      }
    __syncthreads();
  }

  float* Cz = OUTF32 ? (C + (SPLITK ? (size_t)blockIdx.z * (size_t)Mtot * ldc : (size_t)0)) : C;
  int rb = m0 + wm * 64 + kg * 4;              // C/D: row=(lane>>4)*4+reg
  int cb = n0 + wn * 64 + m16;                 //      col=lane&15
#pragma unroll
  for (int j = 0; j < 4; ++j) {
    int col = cb + j * 16;
    float bv = BIAS ? bias[col] : 0.f;
#pragma unroll
    for (int i = 0; i < 4; ++i) {
#pragma unroll
      for (int r = 0; r < 4; ++r) {
        float v = acc[i][j][r] + bv;
        if (RELU) v = fmaxf(v, 0.f);
        int row = rb + i * 16 + r;
        if (OUTF32) {
          Cz[(size_t)row * ldc + col] = v;
        } else {
          _Float16 hh = (_Float16)v;
          Ch[(size_t)row * ldc + col] = hh;
          Cl[(size_t)row * ldc + col] = (_Float16)(v - (float)hh);
        }
      }
    }
  }
}

// ---------------------------------------------------------------------------
// Weight transpose + split:  W [K][N] fp32  ->  Th/Tl [N][K] f16
// ---------------------------------------------------------------------------
__global__ __launch_bounds__(256) void wconv_k(
    const float* __restrict__ W, int K, int N,
    _Float16* __restrict__ Th, _Float16* __restrict__ Tl)
{
  __shared__ float t[32][33];
  int n0 = blockIdx.x * 32, k0 = blockIdx.y * 32;
  int tid = threadIdx.x;
  int r = tid >> 3, c4 = (tid & 7) * 4;
  float4 v = *(const float4*)(W + (size_t)(k0 + r) * N + n0 + c4);
  t[r][c4 + 0] = v.x; t[r][c4 + 1] = v.y; t[r][c4 + 2] = v.z; t[r][c4 + 3] = v.w;
  __syncthreads();
  h4 hi, lo;
#pragma unroll
  for (int i = 0; i < 4; ++i) {
    float x = t[c4 + i][r];
    _Float16 hh = (_Float16)x;
    hi[i] = hh;
    lo[i] = (_Float16)(x - (float)hh);
  }
  *(h4*)(Th + (size_t)(n0 + r) * K + k0 + c4) = hi;
  *(h4*)(Tl + (size_t)(n0 + r) * K + k0 + c4) = lo;
}

// fp32 transpose (optional per-K-row scale):  T[n][ko+k] = W[k][n] * g[k]
__global__ __launch_bounds__(256) void tconv_k(
    const float* __restrict__ W, int N, const float* __restrict__ gvec,
    float* __restrict__ T, int ldT, int ko)
{
  __shared__ float t[32][33];
  int n0 = blockIdx.x * 32, k0 = blockIdx.y * 32;
  int tid = threadIdx.x;
  int r = tid >> 3, c4 = (tid & 7) * 4;
  float4 v = *(const float4*)(W + (size_t)(k0 + r) * N + n0 + c4);
  float s = gvec ? gvec[k0 + r] : 1.f;
  t[r][c4 + 0] = v.x * s; t[r][c4 + 1] = v.y * s;
  t[r][c4 + 2] = v.z * s; t[r][c4 + 3] = v.w * s;
  __syncthreads();
  float4 o;
  o.x = t[c4 + 0][r]; o.y = t[c4 + 1][r]; o.z = t[c4 + 2][r]; o.w = t[c4 + 3][r];
  *(float4*)(T + (size_t)(n0 + r) * ldT + ko + k0 + c4) = o;
}

// u[c] = sum_k g[k]*pw[k][c]; w[c] = sum_k bb[k]*pw[k][c]  (uv[0:512] / uv[512:1024])
__global__ void uv_k(const float* __restrict__ pw, const float* __restrict__ g,
                     const float* __restrict__ bb, float* __restrict__ uv)
{
  int c = blockIdx.x * 256 + threadIdx.x;
  float su = 0.f, sw = 0.f;
  for (int k = 0; k < 512; ++k) {
    float p = pw[(size_t)k * 512 + c];
    su += g[k] * p; sw += bb[k] * p;
  }
  uv[c] = su; uv[512 + c] = sw;
}

// FF2 split-K(4) partial reduce + bias, chunk of 3200x512
__global__ __launch_bounds__(256) void reduce4_k(
    const float* __restrict__ P, const float* __restrict__ bias, float* __restrict__ out)
{
  int idx = blockIdx.x * 256 + threadIdx.x;   // < 3200*512
  const size_t S = 3200ull * 512;
  float v = P[idx] + P[idx + S] + P[idx + 2 * S] + P[idx + 3 * S] + bias[idx & 511];
  out[idx] = v;
}

// ---------------------------------------------------------------------------
// x = node_features @ in_w + in_b + pe   (+ f16 hi/lo planes)
// ---------------------------------------------------------------------------
__global__ __launch_bounds__(256) void input_proj_k(
    const float* __restrict__ nf, const float* __restrict__ inw,
    const float* __restrict__ inb, const float* __restrict__ pe,
    float* __restrict__ x, _Float16* __restrict__ xh, _Float16* __restrict__ xl)
{
  int idx = blockIdx.x * 256 + threadIdx.x;   // < 12800*512
  int bn = idx >> 9, e = idx & 511;
  int n = bn - (bn / Nn) * Nn;
  const float* fr = nf + (size_t)bn * 8;
  float s = inb[e] + pe[(size_t)n * 512 + e];
#pragma unroll
  for (int i = 0; i < 8; ++i) s += fr[i] * inw[(size_t)i * 512 + e];
  x[idx] = s;
  _Float16 hh = (_Float16)s;
  xh[idx] = hh;
  xl[idx] = (_Float16)(s - (float)hh);
}

// ---------------------------------------------------------------------------
// Residual + LayerNorm (rows of 512) + f16 hi/lo planes
// ---------------------------------------------------------------------------
__global__ __launch_bounds__(256) void ln_k(
    const float* __restrict__ xin, const float* __restrict__ yin,
    const float* __restrict__ g, const float* __restrict__ bb,
    float* __restrict__ out, _Float16* __restrict__ oh, _Float16* __restrict__ ol)
{
  int row = blockIdx.x, t = threadIdx.x;
  __shared__ float red[256];
  size_t base = (size_t)row * 512;
  float v0 = xin[base + t] + yin[base + t];
  float v1 = xin[base + 256 + t] + yin[base + 256 + t];
  red[t] = v0 + v1;
  __syncthreads();
  for (int o = 128; o > 0; o >>= 1) { if (t < o) red[t] += red[t + o]; __syncthreads(); }
  float mu = red[0] * (1.f / 512.f);
  __syncthreads();
  float d0 = v0 - mu, d1 = v1 - mu;
  red[t] = d0 * d0 + d1 * d1;
  __syncthreads();
  for (int o = 128; o > 0; o >>= 1) { if (t < o) red[t] += red[t + o]; __syncthreads(); }
  float inv = 1.f / sqrtf(red[0] * (1.f / 512.f) + 1e-5f);
  float y0 = d0 * inv * g[t] + bb[t];
  float y1 = d1 * inv * g[t + 256] + bb[t + 256];
  out[base + t] = y0;
  out[base + 256 + t] = y1;
  _Float16 h0 = (_Float16)y0, h1 = (_Float16)y1;
  oh[base + t] = h0;           ol[base + t] = (_Float16)(y0 - (float)h0);
  oh[base + 256 + t] = h1;     ol[base + 256 + t] = (_Float16)(y1 - (float)h1);
}

// ---------------------------------------------------------------------------
// Fused encoder attention per (b,h); output written as f16 hi/lo planes.
// ---------------------------------------------------------------------------
__global__ __launch_bounds__(256) void enc_attn_k(
    const float* __restrict__ q, const float* __restrict__ k,
    const float* __restrict__ v, _Float16* __restrict__ oh, _Float16* __restrict__ ol)
{
  __shared__ __align__(16) float smem[14848];
  int bh = blockIdx.x; int b = bh >> 3, h = bh & 7;
  int t = threadIdx.x;
  float* qs = smem;           // stride 68
  float* kT = smem + 7616;    // stride 113
  float* p  = smem;           // stride 104 (overlay after phase 1)
  const float* qg = q + ((size_t)b * Nn) * 512 + h * 64;
  const float* kg = k + ((size_t)b * Nn) * 512 + h * 64;
  const float* vg = v + ((size_t)b * Nn) * 512 + h * 64;
  for (int idx = t; idx < 6400; idx += 256) {
    int i = idx >> 6, d = idx & 63;
    qs[i * 68 + d]  = qg[(size_t)i * 512 + d];
    kT[d * 113 + i] = kg[(size_t)i * 512 + d];
  }
  __syncthreads();
  int ti = t >> 4, tj = t & 15;
  int i0 = ti * 7, j0 = tj * 7;
  float s[7][7];
#pragma unroll
  for (int r = 0; r < 7; ++r)
#pragma unroll
    for (int c = 0; c < 7; ++c) s[r][c] = 0.f;
  for (int kk = 0; kk < 64; ++kk) {
    float a[7], bb[7];
#pragma unroll
    for (int r = 0; r < 7; ++r) a[r] = qs[(i0 + r) * 68 + kk];
#pragma unroll
    for (int c = 0; c < 7; ++c) bb[c] = kT[kk * 113 + j0 + c];
#pragma unroll
    for (int r = 0; r < 7; ++r)
#pragma unroll
      for (int c = 0; c < 7; ++c) s[r][c] += a[r] * bb[c];
  }
  __syncthreads();
#pragma unroll
  for (int r = 0; r < 7; ++r)
#pragma unroll
    for (int c = 0; c < 7; ++c) {
      int i = i0 + r, j = j0 + c;
      if (i < Nn && j < Nn) p[i * 104 + j] = s[r][c] * 0.125f;
    }
  __syncthreads();
  int w = t >> 6, lane = t & 63;
  for (int i = w; i < Nn; i += 4) {
    float x0 = p[i * 104 + lane];
    float x1 = (lane < 36) ? p[i * 104 + 64 + lane] : -3.4e38f;
    float mx = fmaxf(x0, x1);
    for (int msk = 32; msk; msk >>= 1) mx = fmaxf(mx, __shfl_xor(mx, msk));
    float e0 = expf(x0 - mx);
    float e1 = (lane < 36) ? expf(x1 - mx) : 0.f;
    float ss = e0 + e1;
    for (int msk = 32; msk; msk >>= 1) ss += __shfl_xor(ss, msk);
    p[i * 104 + lane] = e0 / ss;
    if (lane < 36) p[i * 104 + 64 + lane] = e1 / ss;
  }
  __syncthreads();
  int d0 = tj * 4;
  float oa[7][4];
#pragma unroll
  for (int r = 0; r < 7; ++r)
#pragma unroll
    for (int c = 0; c < 4; ++c) oa[r][c] = 0.f;
  for (int j = 0; j < Nn; ++j) {
    float pr[7];
#pragma unroll
    for (int r = 0; r < 7; ++r) pr[r] = p[(i0 + r) * 104 + j];
    float4 vv = *(const float4*)(vg + (size_t)j * 512 + d0);
#pragma unroll
    for (int r = 0; r < 7; ++r) {
      oa[r][0] += pr[r] * vv.x; oa[r][1] += pr[r] * vv.y;
      oa[r][2] += pr[r] * vv.z; oa[r][3] += pr[r] * vv.w;
    }
  }
  size_t ob = ((size_t)b * Nn) * 512 + h * 64 + d0;
#pragma unroll
  for (int r = 0; r < 7; ++r)
    if (i0 + r < Nn) {
      h4 hv, lv;
#pragma unroll
      for (int c = 0; c < 4; ++c) {
        _Float16 hh = (_Float16)oa[r][c];
        hv[c] = hh;
        lv[c] = (_Float16)(oa[r][c] - (float)hh);
      }
      *(h4*)(oh + ob + (size_t)(i0 + r) * 512) = hv;
      *(h4*)(ol + ob + (size_t)(i0 + r) * 512) = lv;
    }
}

// ---------------------------------------------------------------------------
// decode helpers
// ---------------------------------------------------------------------------
__device__ __forceinline__ float sigm(float x) { return 1.f / (1.f + expf(-x)); }

// stage activation chunk [128 rows][64 k] into LDS in [k][b] layout (stride 129)
__device__ __forceinline__ void stage_act(const float* __restrict__ src, int row_stride,
                                          float* __restrict__ sA, int t)
{
#pragma unroll
  for (int i = 0; i < 8; ++i) {
    int fi = t + i * 256, bb_ = fi >> 4, k4 = fi & 15;
    float4 v = *(const float4*)(src + (size_t)bb_ * row_stride + k4 * 4);
    sA[(k4 * 4 + 0) * 129 + bb_] = v.x;
    sA[(k4 * 4 + 1) * 129 + bb_] = v.y;
    sA[(k4 * 4 + 2) * 129 + bb_] = v.z;
    sA[(k4 * 4 + 3) * 129 + bb_] = v.w;
  }
}

// ---------------------------------------------------------------------------
// K1: gates = [ctx|h] @ WgT^T + biases, LSTM pointwise fused.
// 256 blocks, block j owns h-dims {2j, 2j+1} x 4 gates x all 128 batches.
// ctxh layout per batch: [ctx(512) | hA(512) | hB(512)], stride 1536.
// Reads h slot hin, writes h slot hin^1 (race-free ping-pong).
// done partial: dpart[b][j] = sum_e h2[e]*done_w[e] over the block's dims.
// ---------------------------------------------------------------------------
__global__ __launch_bounds__(256) void lstm_fused_k(
    const float* __restrict__ WgT, const float* __restrict__ bih,
    const float* __restrict__ bhh, float* __restrict__ ctxh,
    float* __restrict__ cbuf, const float* __restrict__ done_w,
    float* __restrict__ dpart, int hin)
{
  __shared__ float sA[64 * 129];
  __shared__ float sW[8 * 68];
  __shared__ float sD[256];
  const int j = blockIdx.x, t = threadIdx.x;
  const int e0 = j * 2;
  const int b = t & 127, half = t >> 7;
  const int e = e0 + half;
  float ai = 0.f, af = 0.f, ag = 0.f, ao = 0.f;
  for (int kt = 0; kt < 1024; kt += 64) {
    const int koff = (kt >= 512 && hin) ? 512 : 0;
    stage_act(ctxh + koff + kt, 1536, sA, t);
    if (t < 128) {
      int r = t >> 4, k4 = t & 15;
      int col = (r >> 1) * 512 + e0 + (r & 1);
      *(float4*)(sW + r * 68 + k4 * 4) = *(const float4*)(WgT + (size_t)col * 1024 + kt + k4 * 4);
    }
    __syncthreads();
    const float* wi = sW + half * 68;   // row (gate*2+half): gate stride = 136
#pragma unroll 8
    for (int k = 0; k < 64; ++k) {
      float a = sA[k * 129 + b];
      ai += a * wi[k];
      af += a * wi[136 + k];
      ag += a * wi[272 + k];
      ao += a * wi[408 + k];
    }
    __syncthreads();
  }
  float ig = ai + bih[e] + bhh[e];
  float fg = af + bih[512 + e] + bhh[512 + e];
  float gg = ag + bih[1024 + e] + bhh[1024 + e];
  float og = ao + bih[1536 + e] + bhh[1536 + e];
  float cp = cbuf[(size_t)b * 512 + e];
  float c2 = sigm(fg) * cp + sigm(ig) * tanhf(gg);
  float h2 = sigm(og) * tanhf(c2);
  cbuf[(size_t)b * 512 + e] = c2;
  ctxh[(size_t)b * 1536 + 1024 - hin * 512 + e] = h2;
  sD[t] = h2 * done_w[e];
  __syncthreads();
  if (t < 128) dpart[(size_t)t * 256 + j] = sD[t] + sD[128 + t];
}

// ---------------------------------------------------------------------------
// K2: q = h2 @ dwqT(+dbq) fused with decoder attention.
// grid (8 batch-tiles of 16, 8 heads); thread = (b in 0..15, ln in 0..15).
// ---------------------------------------------------------------------------
__global__ __launch_bounds__(256) void qattn_k(
    const float* __restrict__ ctxh, const float* __restrict__ dwqT,
    const float* __restrict__ dbq, const float* __restrict__ Kd,
    const float* __restrict__ Vd, float* __restrict__ attno, int hin)
{
  __shared__ float sH[16 * 516];
  __shared__ float sQ[16 * 68];
  __shared__ float sP[16 * 112];
  const int bt = blockIdx.x, h = blockIdx.y;
  const int b0 = bt * 16, t = threadIdx.x;
  const int b = t >> 4, ln = t & 15, d4 = ln * 4;
  const int hbase = 1024 - hin * 512;
#pragma unroll
  for (int i = 0; i < 8; ++i) {
    int fi = t + i * 256, bb_ = fi >> 7, k4 = fi & 127;
    *(float4*)(sH + bb_ * 516 + k4 * 4) =
        *(const float4*)(ctxh + (size_t)(b0 + bb_) * 1536 + hbase + k4 * 4);
  }
  __syncthreads();
  // q projection: 4 output dims per thread
  float qx = 0.f, qy = 0.f, qz = 0.f, qw = 0.f;
  const float* W0 = dwqT + (size_t)(h * 64 + d4) * 512;
  for (int k4 = 0; k4 < 128; ++k4) {
    float4 hv = *(const float4*)(sH + b * 516 + k4 * 4);
    float4 w0 = *(const float4*)(W0 + k4 * 4);
    float4 w1 = *(const float4*)(W0 + 512 + k4 * 4);
    float4 w2 = *(const float4*)(W0 + 1024 + k4 * 4);
    float4 w3 = *(const float4*)(W0 + 1536 + k4 * 4);
    qx += hv.x * w0.x + hv.y * w0.y + hv.z * w0.z + hv.w * w0.w;
    qy += hv.x * w1.x + hv.y * w1.y + hv.z * w1.z + hv.w * w1.w;
    qz += hv.x * w2.x + hv.y * w2.y + hv.z * w2.z + hv.w * w2.w;
    qw += hv.x * w3.x + hv.y * w3.y + hv.z * w3.z + hv.w * w3.w;
  }
  sQ[b * 68 + d4 + 0] = qx + dbq[h * 64 + d4 + 0];
  sQ[b * 68 + d4 + 1] = qy + dbq[h * 64 + d4 + 1];
  sQ[b * 68 + d4 + 2] = qz + dbq[h * 64 + d4 + 2];
  sQ[b * 68 + d4 + 3] = qw + dbq[h * 64 + d4 + 3];
  __syncthreads();
  // scores + register softmax over 16-lane groups
  float sv[7];
  float smax = -3.4e38f;
#pragma unroll
  for (int ni = 0; ni < 7; ++ni) {
    int n = ln + ni * 16;
    float s = -3.4e38f;
    if (n < Nn) {
      const float* kr = Kd + ((size_t)(b0 + b) * Nn + n) * 512 + h * 64;
      float acc = 0.f;
#pragma unroll
      for (int d = 0; d < 16; ++d) {
        float4 kv = *(const float4*)(kr + d * 4);
        float4 qv = *(const float4*)(sQ + b * 68 + d * 4);
        acc += qv.x * kv.x + qv.y * kv.y + qv.z * kv.z + qv.w * kv.w;
      }
      s = acc * 0.125f;
    }
    sv[ni] = s;
    smax = fmaxf(smax, s);
  }
#pragma unroll
  for (int m = 8; m >= 1; m >>= 1) smax = fmaxf(smax, __shfl_xor(smax, m));
  float ssum = 0.f;
#pragma unroll
  for (int ni = 0; ni < 7; ++ni) {
    int n = ln + ni * 16;
    if (n < Nn) { sv[ni] = expf(sv[ni] - smax); ssum += sv[ni]; }
  }
#pragma unroll
  for (int m = 8; m >= 1; m >>= 1) ssum += __shfl_xor(ssum, m);
  float rz = 1.f / ssum;
#pragma unroll
  for (int ni = 0; ni < 7; ++ni) {
    int n = ln + ni * 16;
    if (n < Nn) sP[b * 112 + n] = sv[ni] * rz;
  }
  __syncthreads();
  // PV
  float ox = 0.f, oy = 0.f, oz = 0.f, ow = 0.f;
  const float* vr = Vd + ((size_t)(b0 + b) * Nn) * 512 + h * 64 + d4;
  for (int n = 0; n < Nn; ++n) {
    float p = sP[b * 112 + n];
    float4 vv = *(const float4*)(vr + (size_t)n * 512);
    ox += p * vv.x; oy += p * vv.y; oz += p * vv.z; ow += p * vv.w;
  }
  float4 o4 = {ox, oy, oz, ow};
  *(float4*)(attno + (size_t)(b0 + b) * 512 + h * 64 + d4) = o4;
}

// ---------------------------------------------------------------------------
// K3: Y = attno @ dwoT + dbo (col-tiled, 64 blocks x 8 cols), LN stats partials.
// lnpart[j][b] = {sum_c y, sum_c y^2} over the block's 8 cols.
// ---------------------------------------------------------------------------
__global__ __launch_bounds__(256) void wo_k(
    const float* __restrict__ A, const float* __restrict__ WT,
    const float* __restrict__ bias, float* __restrict__ Y,
    float* __restrict__ lnpart)
{
  __shared__ float sA[64 * 129];
  __shared__ float sW[8 * 68];
  __shared__ float sS1[256];
  __shared__ float sS2[256];
  const int j = blockIdx.x, t = threadIdx.x;
  const int n0 = j * 8;
  const int b = t & 127, half = t >> 7;
  float a0 = 0.f, a1 = 0.f, a2 = 0.f, a3 = 0.f;
  for (int kt = 0; kt < 512; kt += 64) {
    stage_act(A + kt, 512, sA, t);
    if (t < 128) {
      int r = t >> 4, k4 = t & 15;
      *(float4*)(sW + r * 68 + k4 * 4) = *(const float4*)(WT + (size_t)(n0 + r) * 512 + kt + k4 * 4);
    }
    __syncthreads();
    const float* wr = sW + half * 272;   // rows half*4 .. half*4+3
#pragma unroll 8
    for (int k = 0; k < 64; ++k) {
      float a = sA[k * 129 + b];
      a0 += a * wr[k];
      a1 += a * wr[68 + k];
      a2 += a * wr[136 + k];
      a3 += a * wr[204 + k];
    }
    __syncthreads();
  }
  int c0 = n0 + half * 4;
  float y0 = a0 + bias[c0 + 0], y1 = a1 + bias[c0 + 1];
  float y2 = a2 + bias[c0 + 2], y3 = a3 + bias[c0 + 3];
  float4 y4 = {y0, y1, y2, y3};
  *(float4*)(Y + (size_t)b * 512 + c0) = y4;
  sS1[t] = y0 + y1 + y2 + y3;
  sS2[t] = y0 * y0 + y1 * y1 + y2 * y2 + y3 * y3;
  __syncthreads();
  if (t < 128) {
    float2 pr;
    pr.x = sS1[t] + sS1[128 + t];
    pr.y = sS2[t] + sS2[128 + t];
    *(float2*)(lnpart + ((size_t)j * 128 + t) * 2) = pr;
  }
}

// ---------------------------------------------------------------------------
// K4: logits = LN(a) @ dpw + dpb with LN folded in:
//   logits[c] = inv*(a . pwgT[c]) - inv*mu*u[c] + w[c] + dpb[c]
// where pwgT[c][k] = g[k]*pw[k][c], uv = {u | w}. mu/inv from K3 partials.
// ---------------------------------------------------------------------------
__global__ __launch_bounds__(256) void pwln_k(
    const float* __restrict__ A, const float* __restrict__ WT,
    const float* __restrict__ lnpart, const float* __restrict__ uv,
    const float* __restrict__ dpb, float* __restrict__ L)
{
  __shared__ float sA[64 * 129];
  __shared__ float sW[8 * 68];
  __shared__ float sMu[128];
  __shared__ float sInv[128];
  const int j = blockIdx.x, t = threadIdx.x;
  const int n0 = j * 8;
  const int b = t & 127, half = t >> 7;
  if (t < 128) {
    float s1 = 0.f, s2 = 0.f;
    const float2* lp = (const float2*)lnpart;
    for (int jj = 0; jj < 64; ++jj) {
      float2 pr = lp[jj * 128 + t];
      s1 += pr.x; s2 += pr.y;
    }
    float mu = s1 * (1.f / 512.f);
    float var = s2 * (1.f / 512.f) - mu * mu;
    sMu[t] = mu;
    sInv[t] = 1.f / sqrtf(var + 1e-5f);
  }
  float a0 = 0.f, a1 = 0.f, a2 = 0.f, a3 = 0.f;
  for (int kt = 0; kt < 512; kt += 64) {
    stage_act(A + kt, 512, sA, t);
    if (t < 128) {
      int r = t >> 4, k4 = t & 15;
      *(float4*)(sW + r * 68 + k4 * 4) = *(const float4*)(WT + (size_t)(n0 + r) * 512 + kt + k4 * 4);
    }
    __syncthreads();
    const float* wr = sW + half * 272;
#pragma unroll 8
    for (int k = 0; k < 64; ++k) {
      float a = sA[k * 129 + b];
      a0 += a * wr[k];
      a1 += a * wr[68 + k];
      a2 += a * wr[136 + k];
      a3 += a * wr[204 + k];
    }
    __syncthreads();
  }
  int c0 = n0 + half * 4;
  float mu = sMu[b], inv = sInv[b];
  float4 o;
  o.x = inv * a0 - inv * mu * uv[c0 + 0] + uv[512 + c0 + 0] + dpb[c0 + 0];
  o.y = inv * a1 - inv * mu * uv[c0 + 1] + uv[512 + c0 + 1] + dpb[c0 + 1];
  o.z = inv * a2 - inv * mu * uv[c0 + 2] + uv[512 + c0 + 2] + dpb[c0 + 2];
  o.w = inv * a3 - inv * mu * uv[c0 + 3] + uv[512 + c0 + 3] + dpb[c0 + 3];
  *(float4*)(L + (size_t)b * 512 + c0) = o;
}

// ---------------------------------------------------------------------------
__global__ __launch_bounds__(256) void init_k(
    const float* __restrict__ emb, float* __restrict__ ctxh, float* __restrict__ cbuf,
    int* visited, int* ucount, int* complete, int* allvis, int* first, int* prev,
    float* out)
{
  int b = blockIdx.x, t = threadIdx.x;
#pragma unroll
  for (int r = 0; r < 2; ++r) {
    int e = t + 256 * r;
    float s = 0.f;
    for (int i = 0; i < Nn; ++i) s += emb[((size_t)b * Nn + i) * 512 + e];
    ctxh[(size_t)b * 1536 + e] = s / 100.f;
    ctxh[(size_t)b * 1536 + 512 + e] = 0.f;   // h slot0
    cbuf[(size_t)b * 512 + e] = 0.f;
  }
  if (t < Nn) visited[b * Nn + t] = 0;
  if (t == 0) {
    ucount[b] = 0; complete[b] = 0; allvis[b] = 0; first[b] = 0; prev[b] = 0;
    out[150 * Bb + b] = 0.f;
  }
}

// ---------------------------------------------------------------------------
// K5: resolve complete from done-partials, scores vs node_emb, bonus/mask,
// argmax + softmax logp, state update, ctx <- emb[curr].
// ---------------------------------------------------------------------------
__global__ __launch_bounds__(256) void select2_k(
    const float* __restrict__ L, const float* __restrict__ emb, const float* __restrict__ ew,
    const float* __restrict__ dpart, const float* __restrict__ done_b,
    int* visited, int* ucount, int* complete, int* allvis, int* first, int* prev,
    float* __restrict__ ctxh, float* __restrict__ out,
    const float* __restrict__ sb_p, const float* __restrict__ rp_p, int step)
{
  int b = blockIdx.x, t = threadIdx.x;
  __shared__ float lg[512];
  __shared__ float sc[128];
  __shared__ float red[256];
  __shared__ int redi[256];
  __shared__ int s_cm;
  red[t] = dpart[(size_t)b * 256 + t];
  lg[t] = L[(size_t)b * 512 + t];
  lg[t + 256] = L[(size_t)b * 512 + 256 + t];
  __syncthreads();
  for (int o = 128; o > 0; o >>= 1) { if (t < o) red[t] += red[t + o]; __syncthreads(); }
  if (t == 0) {
    int cm = complete[b];
    if (!cm && ucount[b] >= Nn && step >= Nn && (red[0] + done_b[0]) > 0.f) {
      cm = 1; complete[b] = 1;
    }
    s_cm = cm;
  }
  __syncthreads();
  if (t < Nn) {
    const float* er = emb + ((size_t)b * Nn + t) * 512;
    float s = 0.f;
#pragma unroll 8
    for (int e4 = 0; e4 < 128; ++e4) {
      float4 ev = *(const float4*)(er + e4 * 4);
      float4 lv = *(const float4*)(lg + e4 * 4);
      s += lv.x * ev.x + lv.y * ev.y + lv.z * ev.z + lv.w * ev.w;
    }
    int av = allvis[b];
    if (!av && visited[b * Nn + t]) s = rp_p[0];
    if (av) {
      int pv = prev[b];
      float direct = ew[(size_t)b * 10000 + (size_t)pv * 100];
      float via = ew[(size_t)b * 10000 + (size_t)pv * 100 + t] + ew[(size_t)b * 10000 + (size_t)t * 100];
      if (via < direct) s += sb_p[0] * (direct - via) / direct;
    }
    if (s_cm) s = (t == first[b]) ? 100.f : -1e9f;
    sc[t] = s;
  }
  __syncthreads();
  float vv = (t < Nn) ? sc[t] : -3.4e38f;
  int ii = (t < Nn) ? t : 0x7fffffff;
  red[t] = vv; redi[t] = ii;
  __syncthreads();
  for (int o = 128; o > 0; o >>= 1) {
    if (t < o) {
      float v2 = red[t + o]; int i2 = redi[t + o];
      if (v2 > red[t] || (v2 == red[t] && i2 < redi[t])) { red[t] = v2; redi[t] = i2; }
    }
    __syncthreads();
  }
  float m = red[0];
  int curr = redi[0];
  __syncthreads();
  float ex = (t < Nn) ? expf(sc[t] - m) : 0.f;
  red[t] = ex; __syncthreads();
  for (int o = 128; o > 0; o >>= 1) { if (t < o) red[t] += red[t + o]; __syncthreads(); }
  float Z = red[0];
  if (t == 0) {
    float pcur = expf(sc[curr] - m) / Z;
    out[step * Bb + b] = logf(pcur + 1e-10f);
    out[(151 + step) * Bb + b] = (float)curr;
    if (!s_cm) {
      if (!visited[b * Nn + curr]) ucount[b] = ucount[b] + 1;
      visited[b * Nn + curr] = 1;
    }
    if (ucount[b] >= Nn) allvis[b] = 1;
    if (step == 0) first[b] = curr;
    prev[b] = curr;
  }
  const float* src = emb + ((size_t)b * Nn + curr) * 512;
  ctxh[(size_t)b * 1536 + t] = src[t];
  ctxh[(size_t)b * 1536 + t + 256] = src[t + 256];
}

__global__ void final_k(const int* complete, const int* first, float* out)
{
  int b = threadIdx.x;
  out[(151 + 150) * Bb + b] = complete[b] ? 0.f : (float)first[b];
}

// ---------------------------------------------------------------------------
extern "C" void kernel_launch(void* const* d_in, const int* in_sizes, int n_in,
                              void* d_out, int out_size, void* d_ws, size_t ws_size,
                              hipStream_t stream)
{
  const float* nf      = (const float*)d_in[0];
  const float* ew      = (const float*)d_in[1];
  const float* pe      = (const float*)d_in[2];
  const float* in_w    = (const float*)d_in[3];
  const float* in_b    = (const float*)d_in[4];
  const float* enc_wq  = (const float*)d_in[5];
  const float* enc_wk  = (const float*)d_in[6];
  const float* enc_wv  = (const float*)d_in[7];
  const float* enc_wo  = (const float*)d_in[8];
  const float* enc_bq  = (const float*)d_in[9];
  const float* enc_bk  = (const float*)d_in[10];
  const float* enc_bv  = (const float*)d_in[11];
  const float* enc_bo  = (const float*)d_in[12];
  const float* enc_w1  = (const float*)d_in[13];
  const float* enc_b1  = (const float*)d_in[14];
  const float* enc_w2  = (const float*)d_in[15];
  const float* enc_b2  = (const float*)d_in[16];
  const float* ln1g    = (const float*)d_in[17];
  const float* ln1b    = (const float*)d_in[18];
  const float* ln2g    = (const float*)d_in[19];
  const float* ln2b    = (const float*)d_in[20];
  const float* wih     = (const float*)d_in[21];
  const float* whh     = (const float*)d_in[22];
  const float* bih     = (const float*)d_in[23];
  const float* bhh     = (const float*)d_in[24];
  const float* dwq     = (const float*)d_in[25];
  const float* dwk     = (const float*)d_in[26];
  const float* dwv     = (const float*)d_in[27];
  const float* dwo     = (const float*)d_in[28];
  const float* dpw     = (const float*)d_in[29];
  const float* dbq     = (const float*)d_in[30];
  const float* dbk     = (const float*)d_in[31];
  const float* dbv     = (const float*)d_in[32];
  const float* dbo     = (const float*)d_in[33];
  const float* dpb     = (const float*)d_in[34];
  const float* dlng    = (const float*)d_in[35];
  const float* dlnb    = (const float*)d_in[36];
  const float* sbp     = (const float*)d_in[37];
  const float* rpp     = (const float*)d_in[38];
  const float* done_w  = (const float*)d_in[39];
  const float* done_b  = (const float*)d_in[40];
  float* out = (float*)d_out;

  // ---- workspace carve ----
  const size_t SZ = 12800ull * 512;            // 6,553,600 elements
  float* ws = (float*)d_ws;
  float* x   = ws;                              // fp32 node emb
  float* xq  = x + SZ;                          // q / wo-out / ff2-out
  float* xk  = xq + SZ;                         // enc k -> dec K
  float* xv  = xk + SZ;                         // enc v -> FF2 partials -> dec V
  _Float16* xh = (_Float16*)(xv + SZ);          // x hi plane
  _Float16* xl = xh + SZ;                       // x lo plane
  _Float16* oh = xl + SZ;                       // attn-out hi  (alias: FF1-out hi)
  _Float16* ol = oh + SZ;                       // attn-out lo  (alias: FF1-out lo)
  _Float16* wb = ol + SZ;                       // weight planes, 6,291,456 f16
  _Float16* wqh = wb;               _Float16* wql = wqh + 262144;
  _Float16* wkh = wql + 262144;     _Float16* wkl = wkh + 262144;
  _Float16* wvh = wkl + 262144;     _Float16* wvl = wvh + 262144;
  _Float16* woh_ = wvl + 262144;    _Float16* wol_ = woh_ + 262144;
  _Float16* w1h = wol_ + 262144;    _Float16* w1l = w1h + 1048576;
  _Float16* w2h = w1l + 1048576;    _Float16* w2l = w2h + 1048576;
  // decode region (within old decode envelope)
  float* ctxh   = (float*)(w2l + 1048576);      // 128 x 1536 : ctx | hA | hB
  float* cbuf   = ctxh + 196608;                // 128 x 512
  float* dwqT   = cbuf + 65536;                 // 512 x 512
  float* dwoT   = dwqT + 262144;                // 512 x 512
  float* pwgT   = dwoT + 262144;                // 512 x 512 (g-scaled)
  float* uvv    = pwgT + 262144;                // 1024: {u | w}
  float* lnpart = uvv + 1024;                   // 64 x 128 x 2
  float* dpart  = lnpart + 16384;               // 128 x 256
  float* attno  = dpart + 32768;                // 128 x 512 dec-attn out
  float* woO    = attno + 65536;                // 128 x 512 wo out
  float* lgts   = woO + 65536;                  // 128 x 512 logits
  int* ivis     = (int*)(lgts + 65536);
  int* ucount   = ivis + 12800;
  int* complete = ucount + 128;
  int* allvis   = complete + 128;
  int* first    = allvis + 128;
  int* prev     = first + 128;

  // ---- encoder ----
  input_proj_k<<<25600, 256, 0, stream>>>(nf, in_w, in_b, pe, x, xh, xl);

  for (int l = 0; l < Ll; ++l) {
    const float* wq = enc_wq + (size_t)l * 262144;
    const float* wk = enc_wk + (size_t)l * 262144;
    const float* wv = enc_wv + (size_t)l * 262144;
    const float* wo = enc_wo + (size_t)l * 262144;
    const float* bq = enc_bq + (size_t)l * 512;
    const float* bk = enc_bk + (size_t)l * 512;
    const float* bv = enc_bv + (size_t)l * 512;
    const float* bo = enc_bo + (size_t)l * 512;
    const float* w1 = enc_w1 + (size_t)l * 1048576;
    const float* b1 = enc_b1 + (size_t)l * 2048;
    const float* w2 = enc_w2 + (size_t)l * 1048576;
    const float* b2 = enc_b2 + (size_t)l * 512;

    wconv_k<<<dim3(16, 16), 256, 0, stream>>>(wq, 512, 512, wqh, wql);
    wconv_k<<<dim3(16, 16), 256, 0, stream>>>(wk, 512, 512, wkh, wkl);
    wconv_k<<<dim3(16, 16), 256, 0, stream>>>(wv, 512, 512, wvh, wvl);
    wconv_k<<<dim3(16, 16), 256, 0, stream>>>(wo, 512, 512, woh_, wol_);
    wconv_k<<<dim3(64, 16), 256, 0, stream>>>(w1, 512, 2048, w1h, w1l);
    wconv_k<<<dim3(16, 64), 256, 0, stream>>>(w2, 2048, 512, w2h, w2l);

    mgemm_k<false, true, true, false><<<dim3(4, 100), 256, 0, stream>>>(
        xh, xl, 512, wqh, wql, 512, xq, nullptr, nullptr, 512, bq, 512, 0, 0);
    mgemm_k<false, true, true, false><<<dim3(4, 100), 256, 0, stream>>>(
        xh, xl, 512, wkh, wkl, 512, xk, nullptr, nullptr, 512, bk, 512, 0, 0);
    mgemm_k<false, true, true, false><<<dim3(4, 100), 256, 0, stream>>>(
        xh, xl, 512, wvh, wvl, 512, xv, nullptr, nullptr, 512, bv, 512, 0, 0);
    enc_attn_k<<<1024, 256, 0, stream>>>(xq, xk, xv, oh, ol);
    mgemm_k<false, true, true, false><<<dim3(4, 100), 256, 0, stream>>>(
        oh, ol, 512, woh_, wol_, 512, xq, nullptr, nullptr, 512, bo, 512, 0, 0);
    ln_k<<<12800, 256, 0, stream>>>(x, xq, ln1g + l * 512, ln1b + l * 512, x, xh, xl);
    for (int c = 0; c < 4; ++c) {
      mgemm_k<true, true, false, false><<<dim3(16, 25), 256, 0, stream>>>(
          xh + (size_t)c * 3200 * 512, xl + (size_t)c * 3200 * 512, 512,
          w1h, w1l, 512, nullptr, oh, ol, 2048, b1, 512, 0, 0);
      mgemm_k<false, false, true, true><<<dim3(4, 25, 4), 256, 0, stream>>>(
          oh, ol, 2048, w2h, w2l, 2048, xv, nullptr, nullptr, 512,
          nullptr, 2048, 512, 3200);
      reduce4_k<<<6400, 256, 0, stream>>>(xv, b2, xq + (size_t)c * 3200 * 512);
    }
    ln_k<<<12800, 256, 0, stream>>>(x, xq, ln2g + l * 512, ln2b + l * 512, x, xh, xl);
  }

  // ---- decode prep: K/V step-invariant ----
  wconv_k<<<dim3(16, 16), 256, 0, stream>>>(dwk, 512, 512, wqh, wql);
  wconv_k<<<dim3(16, 16), 256, 0, stream>>>(dwv, 512, 512, wkh, wkl);
  mgemm_k<false, true, true, false><<<dim3(4, 100), 256, 0, stream>>>(
      xh, xl, 512, wqh, wql, 512, xk, nullptr, nullptr, 512, dbk, 512, 0, 0);
  mgemm_k<false, true, true, false><<<dim3(4, 100), 256, 0, stream>>>(
      xh, xl, 512, wkh, wkl, 512, xv, nullptr, nullptr, 512, dbv, 512, 0, 0);

  // one-time decode weight transposes (wb region is dead after the mgemms above)
  float* WgT = (float*)wb;                      // 2048 x 1024 fp32 (fits in wb)
  tconv_k<<<dim3(64, 16), 256, 0, stream>>>(wih, 2048, nullptr, WgT, 1024, 0);
  tconv_k<<<dim3(64, 16), 256, 0, stream>>>(whh, 2048, nullptr, WgT, 1024, 512);
  tconv_k<<<dim3(16, 16), 256, 0, stream>>>(dwq, 512, nullptr, dwqT, 512, 0);
  tconv_k<<<dim3(16, 16), 256, 0, stream>>>(dwo, 512, nullptr, dwoT, 512, 0);
  tconv_k<<<dim3(16, 16), 256, 0, stream>>>(dpw, 512, dlng, pwgT, 512, 0);
  uv_k<<<2, 256, 0, stream>>>(dpw, dlng, dlnb, uvv);
  init_k<<<128, 256, 0, stream>>>(x, ctxh, cbuf, ivis, ucount, complete, allvis, first, prev, out);

  // ---- decode loop: 5 kernels/step ----
  for (int step = 0; step < STEPS; ++step) {
    int hin = step & 1;
    lstm_fused_k<<<256, 256, 0, stream>>>(WgT, bih, bhh, ctxh, cbuf, done_w, dpart, hin);
    qattn_k<<<dim3(8, 8), 256, 0, stream>>>(ctxh, dwqT, dbq, xk, xv, attno, hin);
    wo_k<<<64, 256, 0, stream>>>(attno, dwoT, dbo, woO, lnpart);
    pwln_k<<<64, 256, 0, stream>>>(woO, pwgT, lnpart, uvv, dpb, lgts);
    select2_k<<<128, 256, 0, stream>>>(lgts, x, ew, dpart, done_b, ivis, ucount, complete,
                                       allvis, first, prev, ctxh, out, sbp, rpp, step);
  }
  final_k<<<1, 128, 0, stream>>>(complete, first, out);
}

// Round 2
// 29950.488 us; speedup vs baseline: 1.0207x; 1.0207x over previous
//
#include <hip/hip_runtime.h>
#include <math.h>

#define Bb 128
#define Nn 100
#define Ee 512
#define Hh 8
#define DHd 64
#define FFf 2048
#define Ll 6
#define STEPS 150

typedef _Float16 h8 __attribute__((ext_vector_type(8)));
typedef _Float16 h4 __attribute__((ext_vector_type(4)));
typedef float f4 __attribute__((ext_vector_type(4)));

// ---------------------------------------------------------------------------
// Split-f16 MFMA GEMM.  C[M,N] = A[M,K] @ B[K,N] computed as
// Ah*Bh + Ah*Bl + Al*Bh with f16 hi/lo planes (pre-split inputs).
// A planes: [M][K] f16.  B planes: pre-transposed [N][K] f16.
// Tile 128x128, BK=32, 4 waves (2x2), each wave 4x4 frags of 16x16x32.
// OUTF32: fp32 (+bias,+relu).  else: write f16 hi/lo planes (+bias,+relu).
// SPLITK: blockIdx.z picks K-chunk kc, partial to C + z*Mtot*ldc, no bias.
// ---------------------------------------------------------------------------
template<bool RELU, bool BIAS, bool OUTF32, bool SPLITK>
__global__ __launch_bounds__(256) void mgemm_k(
    const _Float16* __restrict__ Ah, const _Float16* __restrict__ Al, int lda,
    const _Float16* __restrict__ Bh, const _Float16* __restrict__ Bl, int ldb,
    float* __restrict__ C, _Float16* __restrict__ Ch, _Float16* __restrict__ Cl,
    int ldc, const float* __restrict__ bias, int K, int kc, int Mtot)
{
  __shared__ _Float16 sm[4 * 5120];            // 4 planes of 128 x (32+8pad)
  _Float16* sAh = sm;
  _Float16* sAl = sm + 5120;
  _Float16* sBh = sm + 10240;
  _Float16* sBl = sm + 15360;
  const int tid = threadIdx.x;
  const int m0 = blockIdx.y * 128, n0 = blockIdx.x * 128;
  const int k0 = SPLITK ? blockIdx.z * kc : 0;
  const int kEnd = SPLITK ? k0 + kc : K;
  const int lane = tid & 63, wave = tid >> 6;
  const int wm = wave >> 1, wn = wave & 1;
  const int m16 = lane & 15, kg = lane >> 4;
  f4 acc[4][4];
#pragma unroll
  for (int i = 0; i < 4; ++i)
#pragma unroll
    for (int j = 0; j < 4; ++j) acc[i][j] = (f4)0.f;

  for (int kt = k0; kt < kEnd; kt += 32) {
#pragma unroll
    for (int it = 0; it < 2; ++it) {
      int idx = tid + it * 256;                // 512 (row,g) slots
      int row = idx >> 2, g = idx & 3;
      int lo_ = row * 40 + g * 8;
      size_t ga = (size_t)(m0 + row) * lda + kt + g * 8;
      size_t gb = (size_t)(n0 + row) * ldb + kt + g * 8;
      *(h8*)(sAh + lo_) = *(const h8*)(Ah + ga);
      *(h8*)(sAl + lo_) = *(const h8*)(Al + ga);
      *(h8*)(sBh + lo_) = *(const h8*)(Bh + gb);
      *(h8*)(sBl + lo_) = *(const h8*)(Bl + gb);
    }
    __syncthreads();
    h8 a_h[4], a_l[4], b_h[4], b_l[4];
#pragma unroll
    for (int i = 0; i < 4; ++i) {
      int ro = (wm * 64 + i * 16 + m16) * 40 + kg * 8;
      int co = (wn * 64 + i * 16 + m16) * 40 + kg * 8;
      a_h[i] = *(const h8*)(sAh + ro);
      a_l[i] = *(const h8*)(sAl + ro);
      b_h[i] = *(const h8*)(sBh + co);
      b_l[i] = *(const h8*)(sBl + co);
    }
#pragma unroll
    for (int i = 0; i < 4; ++i)
#pragma unroll
      for (int j = 0; j < 4; ++j) {
        acc[i][j] = __builtin_amdgcn_mfma_f32_16x16x32_f16(a_h[i], b_h[j], acc[i][j], 0, 0, 0);
        acc[i][j] = __builtin_amdgcn_mfma_f32_16x16x32_f16(a_h[i], b_l[j], acc[i][j], 0, 0, 0);
        acc[i][j] = __builtin_amdgcn_mfma_f32_16x16x32_f16(a_l[i], b_h[j], acc[i][j], 0, 0, 0);
      }
    __syncthreads();
  }

  float* Cz = OUTF32 ? (C + (SPLITK ? (size_t)blockIdx.z * (size_t)Mtot * ldc : (size_t)0)) : C;
  int rb = m0 + wm * 64 + kg * 4;              // C/D: row=(lane>>4)*4+reg
  int cb = n0 + wn * 64 + m16;                 //      col=lane&15
#pragma unroll
  for (int j = 0; j < 4; ++j) {
    int col = cb + j * 16;
    float bv = BIAS ? bias[col] : 0.f;
#pragma unroll
    for (int i = 0; i < 4; ++i) {
#pragma unroll
      for (int r = 0; r < 4; ++r) {
        float v = acc[i][j][r] + bv;
        if (RELU) v = fmaxf(v, 0.f);
        int row = rb + i * 16 + r;
        if (OUTF32) {
          Cz[(size_t)row * ldc + col] = v;
        } else {
          _Float16 hh = (_Float16)v;
          Ch[(size_t)row * ldc + col] = hh;
          Cl[(size_t)row * ldc + col] = (_Float16)(v - (float)hh);
        }
      }
    }
  }
}

// ---------------------------------------------------------------------------
// Weight transpose + split:  W [K][N] fp32  ->  Th/Tl [N][K] f16
// ---------------------------------------------------------------------------
__global__ __launch_bounds__(256) void wconv_k(
    const float* __restrict__ W, int K, int N,
    _Float16* __restrict__ Th, _Float16* __restrict__ Tl)
{
  __shared__ float t[32][33];
  int n0 = blockIdx.x * 32, k0 = blockIdx.y * 32;
  int tid = threadIdx.x;
  int r = tid >> 3, c4 = (tid & 7) * 4;
  float4 v = *(const float4*)(W + (size_t)(k0 + r) * N + n0 + c4);
  t[r][c4 + 0] = v.x; t[r][c4 + 1] = v.y; t[r][c4 + 2] = v.z; t[r][c4 + 3] = v.w;
  __syncthreads();
  h4 hi, lo;
#pragma unroll
  for (int i = 0; i < 4; ++i) {
    float x = t[c4 + i][r];
    _Float16 hh = (_Float16)x;
    hi[i] = hh;
    lo[i] = (_Float16)(x - (float)hh);
  }
  *(h4*)(Th + (size_t)(n0 + r) * K + k0 + c4) = hi;
  *(h4*)(Tl + (size_t)(n0 + r) * K + k0 + c4) = lo;
}

// fp32 transpose (optional per-K-row scale):  T[n][ko+k] = W[k][n] * g[k]
__global__ __launch_bounds__(256) void tconv_k(
    const float* __restrict__ W, int N, const float* __restrict__ gvec,
    float* __restrict__ T, int ldT, int ko)
{
  __shared__ float t[32][33];
  int n0 = blockIdx.x * 32, k0 = blockIdx.y * 32;
  int tid = threadIdx.x;
  int r = tid >> 3, c4 = (tid & 7) * 4;
  float4 v = *(const float4*)(W + (size_t)(k0 + r) * N + n0 + c4);
  float s = gvec ? gvec[k0 + r] : 1.f;
  t[r][c4 + 0] = v.x * s; t[r][c4 + 1] = v.y * s;
  t[r][c4 + 2] = v.z * s; t[r][c4 + 3] = v.w * s;
  __syncthreads();
  float4 o;
  o.x = t[c4 + 0][r]; o.y = t[c4 + 1][r]; o.z = t[c4 + 2][r]; o.w = t[c4 + 3][r];
  *(float4*)(T + (size_t)(n0 + r) * ldT + ko + k0 + c4) = o;
}

// u[c] = sum_k g[k]*pw[k][c]; w[c] = sum_k bb[k]*pw[k][c]  (uv[0:512] / uv[512:1024])
__global__ void uv_k(const float* __restrict__ pw, const float* __restrict__ g,
                     const float* __restrict__ bb, float* __restrict__ uv)
{
  int c = blockIdx.x * 256 + threadIdx.x;
  float su = 0.f, sw = 0.f;
  for (int k = 0; k < 512; ++k) {
    float p = pw[(size_t)k * 512 + c];
    su += g[k] * p; sw += bb[k] * p;
  }
  uv[c] = su; uv[512 + c] = sw;
}

// FF2 split-K(4) partial reduce + bias, chunk of 3200x512
__global__ __launch_bounds__(256) void reduce4_k(
    const float* __restrict__ P, const float* __restrict__ bias, float* __restrict__ out)
{
  int idx = blockIdx.x * 256 + threadIdx.x;   // < 3200*512
  const size_t S = 3200ull * 512;
  float v = P[idx] + P[idx + S] + P[idx + 2 * S] + P[idx + 3 * S] + bias[idx & 511];
  out[idx] = v;
}

// ---------------------------------------------------------------------------
// x = node_features @ in_w + in_b + pe   (+ f16 hi/lo planes)
// ---------------------------------------------------------------------------
__global__ __launch_bounds__(256) void input_proj_k(
    const float* __restrict__ nf, const float* __restrict__ inw,
    const float* __restrict__ inb, const float* __restrict__ pe,
    float* __restrict__ x, _Float16* __restrict__ xh, _Float16* __restrict__ xl)
{
  int idx = blockIdx.x * 256 + threadIdx.x;   // < 12800*512
  int bn = idx >> 9, e = idx & 511;
  int n = bn - (bn / Nn) * Nn;
  const float* fr = nf + (size_t)bn * 8;
  float s = inb[e] + pe[(size_t)n * 512 + e];
#pragma unroll
  for (int i = 0; i < 8; ++i) s += fr[i] * inw[(size_t)i * 512 + e];
  x[idx] = s;
  _Float16 hh = (_Float16)s;
  xh[idx] = hh;
  xl[idx] = (_Float16)(s - (float)hh);
}

// ---------------------------------------------------------------------------
// Residual + LayerNorm (rows of 512) + f16 hi/lo planes
// ---------------------------------------------------------------------------
__global__ __launch_bounds__(256) void ln_k(
    const float* __restrict__ xin, const float* __restrict__ yin,
    const float* __restrict__ g, const float* __restrict__ bb,
    float* __restrict__ out, _Float16* __restrict__ oh, _Float16* __restrict__ ol)
{
  int row = blockIdx.x, t = threadIdx.x;
  __shared__ float red[256];
  size_t base = (size_t)row * 512;
  float v0 = xin[base + t] + yin[base + t];
  float v1 = xin[base + 256 + t] + yin[base + 256 + t];
  red[t] = v0 + v1;
  __syncthreads();
  for (int o = 128; o > 0; o >>= 1) { if (t < o) red[t] += red[t + o]; __syncthreads(); }
  float mu = red[0] * (1.f / 512.f);
  __syncthreads();
  float d0 = v0 - mu, d1 = v1 - mu;
  red[t] = d0 * d0 + d1 * d1;
  __syncthreads();
  for (int o = 128; o > 0; o >>= 1) { if (t < o) red[t] += red[t + o]; __syncthreads(); }
  float inv = 1.f / sqrtf(red[0] * (1.f / 512.f) + 1e-5f);
  float y0 = d0 * inv * g[t] + bb[t];
  float y1 = d1 * inv * g[t + 256] + bb[t + 256];
  out[base + t] = y0;
  out[base + 256 + t] = y1;
  _Float16 h0 = (_Float16)y0, h1 = (_Float16)y1;
  oh[base + t] = h0;           ol[base + t] = (_Float16)(y0 - (float)h0);
  oh[base + 256 + t] = h1;     ol[base + 256 + t] = (_Float16)(y1 - (float)h1);
}

// ---------------------------------------------------------------------------
// Fused encoder attention per (b,h); output written as f16 hi/lo planes.
// ---------------------------------------------------------------------------
__global__ __launch_bounds__(256) void enc_attn_k(
    const float* __restrict__ q, const float* __restrict__ k,
    const float* __restrict__ v, _Float16* __restrict__ oh, _Float16* __restrict__ ol)
{
  __shared__ __align__(16) float smem[14848];
  int bh = blockIdx.x; int b = bh >> 3, h = bh & 7;
  int t = threadIdx.x;
  float* qs = smem;           // stride 68
  float* kT = smem + 7616;    // stride 113
  float* p  = smem;           // stride 104 (overlay after phase 1)
  const float* qg = q + ((size_t)b * Nn) * 512 + h * 64;
  const float* kg = k + ((size_t)b * Nn) * 512 + h * 64;
  const float* vg = v + ((size_t)b * Nn) * 512 + h * 64;
  for (int idx = t; idx < 6400; idx += 256) {
    int i = idx >> 6, d = idx & 63;
    qs[i * 68 + d]  = qg[(size_t)i * 512 + d];
    kT[d * 113 + i] = kg[(size_t)i * 512 + d];
  }
  __syncthreads();
  int ti = t >> 4, tj = t & 15;
  int i0 = ti * 7, j0 = tj * 7;
  float s[7][7];
#pragma unroll
  for (int r = 0; r < 7; ++r)
#pragma unroll
    for (int c = 0; c < 7; ++c) s[r][c] = 0.f;
  for (int kk = 0; kk < 64; ++kk) {
    float a[7], bb[7];
#pragma unroll
    for (int r = 0; r < 7; ++r) a[r] = qs[(i0 + r) * 68 + kk];
#pragma unroll
    for (int c = 0; c < 7; ++c) bb[c] = kT[kk * 113 + j0 + c];
#pragma unroll
    for (int r = 0; r < 7; ++r)
#pragma unroll
      for (int c = 0; c < 7; ++c) s[r][c] += a[r] * bb[c];
  }
  __syncthreads();
#pragma unroll
  for (int r = 0; r < 7; ++r)
#pragma unroll
    for (int c = 0; c < 7; ++c) {
      int i = i0 + r, j = j0 + c;
      if (i < Nn && j < Nn) p[i * 104 + j] = s[r][c] * 0.125f;
    }
  __syncthreads();
  int w = t >> 6, lane = t & 63;
  for (int i = w; i < Nn; i += 4) {
    float x0 = p[i * 104 + lane];
    float x1 = (lane < 36) ? p[i * 104 + 64 + lane] : -3.4e38f;
    float mx = fmaxf(x0, x1);
    for (int msk = 32; msk; msk >>= 1) mx = fmaxf(mx, __shfl_xor(mx, msk));
    float e0 = expf(x0 - mx);
    float e1 = (lane < 36) ? expf(x1 - mx) : 0.f;
    float ss = e0 + e1;
    for (int msk = 32; msk; msk >>= 1) ss += __shfl_xor(ss, msk);
    p[i * 104 + lane] = e0 / ss;
    if (lane < 36) p[i * 104 + 64 + lane] = e1 / ss;
  }
  __syncthreads();
  int d0 = tj * 4;
  float oa[7][4];
#pragma unroll
  for (int r = 0; r < 7; ++r)
#pragma unroll
    for (int c = 0; c < 4; ++c) oa[r][c] = 0.f;
  for (int j = 0; j < Nn; ++j) {
    float pr[7];
#pragma unroll
    for (int r = 0; r < 7; ++r) pr[r] = p[(i0 + r) * 104 + j];
    float4 vv = *(const float4*)(vg + (size_t)j * 512 + d0);
#pragma unroll
    for (int r = 0; r < 7; ++r) {
      oa[r][0] += pr[r] * vv.x; oa[r][1] += pr[r] * vv.y;
      oa[r][2] += pr[r] * vv.z; oa[r][3] += pr[r] * vv.w;
    }
  }
  size_t ob = ((size_t)b * Nn) * 512 + h * 64 + d0;
#pragma unroll
  for (int r = 0; r < 7; ++r)
    if (i0 + r < Nn) {
      h4 hv, lv;
#pragma unroll
      for (int c = 0; c < 4; ++c) {
        _Float16 hh = (_Float16)oa[r][c];
        hv[c] = hh;
        lv[c] = (_Float16)(oa[r][c] - (float)hh);
      }
      *(h4*)(oh + ob + (size_t)(i0 + r) * 512) = hv;
      *(h4*)(ol + ob + (size_t)(i0 + r) * 512) = lv;
    }
}

// ---------------------------------------------------------------------------
// decode helpers
// ---------------------------------------------------------------------------
__device__ __forceinline__ float sigm(float x) { return 1.f / (1.f + expf(-x)); }

// stage activation chunk [128 rows][64 k] into LDS as float2[kk][b], kk=k/2,
// row stride 131 float2 (chosen so write/read bank spread is >=8 banks).
__device__ __forceinline__ void stage_act2(const float* __restrict__ src, int row_stride,
                                           float2* __restrict__ sA, int t)
{
#pragma unroll
  for (int i = 0; i < 8; ++i) {
    int fi = t + i * 256, bb_ = fi >> 4, k4 = fi & 15;
    float4 v = *(const float4*)(src + (size_t)bb_ * row_stride + k4 * 4);
    float2 p0; p0.x = v.x; p0.y = v.y;
    float2 p1; p1.x = v.z; p1.y = v.w;
    sA[(k4 * 2 + 0) * 131 + bb_] = p0;
    sA[(k4 * 2 + 1) * 131 + bb_] = p1;
  }
}

// ---------------------------------------------------------------------------
// K1: gates = [ctx|h] @ WgT^T + biases, LSTM pointwise fused.
// 256 blocks, block j owns h-dims {2j, 2j+1} x 4 gates x all 128 batches.
// ctxh layout per batch: [ctx(512) | hA(512) | hB(512)], stride 1536.
// Reads h slot hin, writes h slot hin^1 (race-free ping-pong).
// done partial: dpart[b][j] = sum_e h2[e]*done_w[e] over the block's dims.
// Inner loop float2: 5 LDS instrs per 8 FMAs (b64 act + 4 b64 broadcasts).
// ---------------------------------------------------------------------------
__global__ __launch_bounds__(256) void lstm_fused_k(
    const float* __restrict__ WgT, const float* __restrict__ bih,
    const float* __restrict__ bhh, float* __restrict__ ctxh,
    float* __restrict__ cbuf, const float* __restrict__ done_w,
    float* __restrict__ dpart, int hin)
{
  __shared__ float2 sA2[32 * 131];
  __shared__ float2 sW2[8 * 34];
  __shared__ float sD[256];
  const int j = blockIdx.x, t = threadIdx.x;
  const int e0 = j * 2;
  const int b = t & 127, half = t >> 7;
  const int e = e0 + half;
  float ai = 0.f, af = 0.f, ag = 0.f, ao = 0.f;
  for (int kt = 0; kt < 1024; kt += 64) {
    const int koff = (kt >= 512 && hin) ? 512 : 0;
    stage_act2(ctxh + koff + kt, 1536, sA2, t);
    if (t < 128) {
      int r = t >> 4, k4 = t & 15;
      int col = (r >> 1) * 512 + e0 + (r & 1);
      float4 w = *(const float4*)(WgT + (size_t)col * 1024 + kt + k4 * 4);
      float2 p0; p0.x = w.x; p0.y = w.y;
      float2 p1; p1.x = w.z; p1.y = w.w;
      sW2[r * 34 + k4 * 2 + 0] = p0;
      sW2[r * 34 + k4 * 2 + 1] = p1;
    }
    __syncthreads();
    const float2* wi = sW2 + half * 34;   // row (gate*2+half): gate stride = 68 f2
#pragma unroll 8
    for (int kk = 0; kk < 32; ++kk) {
      float2 a  = sA2[kk * 131 + b];
      float2 w0 = wi[kk];
      float2 w1 = wi[68 + kk];
      float2 w2 = wi[136 + kk];
      float2 w3 = wi[204 + kk];
      ai += a.x * w0.x + a.y * w0.y;
      af += a.x * w1.x + a.y * w1.y;
      ag += a.x * w2.x + a.y * w2.y;
      ao += a.x * w3.x + a.y * w3.y;
    }
    __syncthreads();
  }
  float ig = ai + bih[e] + bhh[e];
  float fg = af + bih[512 + e] + bhh[512 + e];
  float gg = ag + bih[1024 + e] + bhh[1024 + e];
  float og = ao + bih[1536 + e] + bhh[1536 + e];
  float cp = cbuf[(size_t)b * 512 + e];
  float c2 = sigm(fg) * cp + sigm(ig) * tanhf(gg);
  float h2 = sigm(og) * tanhf(c2);
  cbuf[(size_t)b * 512 + e] = c2;
  ctxh[(size_t)b * 1536 + 1024 - hin * 512 + e] = h2;
  sD[t] = h2 * done_w[e];
  __syncthreads();
  if (t < 128) dpart[(size_t)t * 256 + j] = sD[t] + sD[128 + t];
}

// ---------------------------------------------------------------------------
// K2: q = h2 @ dwqT(+dbq) fused with decoder attention.
// grid (8 batch-tiles of 16, 8 heads); thread = (b in 0..15, ln in 0..15).
// ---------------------------------------------------------------------------
__global__ __launch_bounds__(256) void qattn_k(
    const float* __restrict__ ctxh, const float* __restrict__ dwqT,
    const float* __restrict__ dbq, const float* __restrict__ Kd,
    const float* __restrict__ Vd, float* __restrict__ attno, int hin)
{
  __shared__ float sH[16 * 516];
  __shared__ float sQ[16 * 68];
  __shared__ float sP[16 * 112];
  const int bt = blockIdx.x, h = blockIdx.y;
  const int b0 = bt * 16, t = threadIdx.x;
  const int b = t >> 4, ln = t & 15, d4 = ln * 4;
  const int hbase = 1024 - hin * 512;
#pragma unroll
  for (int i = 0; i < 8; ++i) {
    int fi = t + i * 256, bb_ = fi >> 7, k4 = fi & 127;
    *(float4*)(sH + bb_ * 516 + k4 * 4) =
        *(const float4*)(ctxh + (size_t)(b0 + bb_) * 1536 + hbase + k4 * 4);
  }
  __syncthreads();
  // q projection: 4 output dims per thread
  float qx = 0.f, qy = 0.f, qz = 0.f, qw = 0.f;
  const float* W0 = dwqT + (size_t)(h * 64 + d4) * 512;
  for (int k4 = 0; k4 < 128; ++k4) {
    float4 hv = *(const float4*)(sH + b * 516 + k4 * 4);
    float4 w0 = *(const float4*)(W0 + k4 * 4);
    float4 w1 = *(const float4*)(W0 + 512 + k4 * 4);
    float4 w2 = *(const float4*)(W0 + 1024 + k4 * 4);
    float4 w3 = *(const float4*)(W0 + 1536 + k4 * 4);
    qx += hv.x * w0.x + hv.y * w0.y + hv.z * w0.z + hv.w * w0.w;
    qy += hv.x * w1.x + hv.y * w1.y + hv.z * w1.z + hv.w * w1.w;
    qz += hv.x * w2.x + hv.y * w2.y + hv.z * w2.z + hv.w * w2.w;
    qw += hv.x * w3.x + hv.y * w3.y + hv.z * w3.z + hv.w * w3.w;
  }
  sQ[b * 68 + d4 + 0] = qx + dbq[h * 64 + d4 + 0];
  sQ[b * 68 + d4 + 1] = qy + dbq[h * 64 + d4 + 1];
  sQ[b * 68 + d4 + 2] = qz + dbq[h * 64 + d4 + 2];
  sQ[b * 68 + d4 + 3] = qw + dbq[h * 64 + d4 + 3];
  __syncthreads();
  // scores + register softmax over 16-lane groups
  float sv[7];
  float smax = -3.4e38f;
#pragma unroll
  for (int ni = 0; ni < 7; ++ni) {
    int n = ln + ni * 16;
    float s = -3.4e38f;
    if (n < Nn) {
      const float* kr = Kd + ((size_t)(b0 + b) * Nn + n) * 512 + h * 64;
      float acc = 0.f;
#pragma unroll
      for (int d = 0; d < 16; ++d) {
        float4 kv = *(const float4*)(kr + d * 4);
        float4 qv = *(const float4*)(sQ + b * 68 + d * 4);
        acc += qv.x * kv.x + qv.y * kv.y + qv.z * kv.z + qv.w * kv.w;
      }
      s = acc * 0.125f;
    }
    sv[ni] = s;
    smax = fmaxf(smax, s);
  }
#pragma unroll
  for (int m = 8; m >= 1; m >>= 1) smax = fmaxf(smax, __shfl_xor(smax, m));
  float ssum = 0.f;
#pragma unroll
  for (int ni = 0; ni < 7; ++ni) {
    int n = ln + ni * 16;
    if (n < Nn) { sv[ni] = expf(sv[ni] - smax); ssum += sv[ni]; }
  }
#pragma unroll
  for (int m = 8; m >= 1; m >>= 1) ssum += __shfl_xor(ssum, m);
  float rz = 1.f / ssum;
#pragma unroll
  for (int ni = 0; ni < 7; ++ni) {
    int n = ln + ni * 16;
    if (n < Nn) sP[b * 112 + n] = sv[ni] * rz;
  }
  __syncthreads();
  // PV
  float ox = 0.f, oy = 0.f, oz = 0.f, ow = 0.f;
  const float* vr = Vd + ((size_t)(b0 + b) * Nn) * 512 + h * 64 + d4;
  for (int n = 0; n < Nn; ++n) {
    float p = sP[b * 112 + n];
    float4 vv = *(const float4*)(vr + (size_t)n * 512);
    ox += p * vv.x; oy += p * vv.y; oz += p * vv.z; ow += p * vv.w;
  }
  float4 o4 = {ox, oy, oz, ow};
  *(float4*)(attno + (size_t)(b0 + b) * 512 + h * 64 + d4) = o4;
}

// ---------------------------------------------------------------------------
// K3: Y = attno @ dwoT + dbo (col-tiled, 64 blocks x 8 cols), LN stats partials.
// lnpart[j][b] = {sum_c y, sum_c y^2} over the block's 8 cols.
// ---------------------------------------------------------------------------
__global__ __launch_bounds__(256) void wo_k(
    const float* __restrict__ A, const float* __restrict__ WT,
    const float* __restrict__ bias, float* __restrict__ Y,
    float* __restrict__ lnpart)
{
  __shared__ float2 sA2[32 * 131];
  __shared__ float2 sW2[8 * 34];
  __shared__ float sS1[256];
  __shared__ float sS2[256];
  const int j = blockIdx.x, t = threadIdx.x;
  const int n0 = j * 8;
  const int b = t & 127, half = t >> 7;
  float a0 = 0.f, a1 = 0.f, a2 = 0.f, a3 = 0.f;
  for (int kt = 0; kt < 512; kt += 64) {
    stage_act2(A + kt, 512, sA2, t);
    if (t < 128) {
      int r = t >> 4, k4 = t & 15;
      float4 w = *(const float4*)(WT + (size_t)(n0 + r) * 512 + kt + k4 * 4);
      float2 p0; p0.x = w.x; p0.y = w.y;
      float2 p1; p1.x = w.z; p1.y = w.w;
      sW2[r * 34 + k4 * 2 + 0] = p0;
      sW2[r * 34 + k4 * 2 + 1] = p1;
    }
    __syncthreads();
    const float2* wr = sW2 + half * 136;   // rows half*4 .. half*4+3
#pragma unroll 8
    for (int kk = 0; kk < 32; ++kk) {
      float2 a  = sA2[kk * 131 + b];
      float2 w0 = wr[kk];
      float2 w1 = wr[34 + kk];
      float2 w2 = wr[68 + kk];
      float2 w3 = wr[102 + kk];
      a0 += a.x * w0.x + a.y * w0.y;
      a1 += a.x * w1.x + a.y * w1.y;
      a2 += a.x * w2.x + a.y * w2.y;
      a3 += a.x * w3.x + a.y * w3.y;
    }
    __syncthreads();
  }
  int c0 = n0 + half * 4;
  float y0 = a0 + bias[c0 + 0], y1 = a1 + bias[c0 + 1];
  float y2 = a2 + bias[c0 + 2], y3 = a3 + bias[c0 + 3];
  float4 y4 = {y0, y1, y2, y3};
  *(float4*)(Y + (size_t)b * 512 + c0) = y4;
  sS1[t] = y0 + y1 + y2 + y3;
  sS2[t] = y0 * y0 + y1 * y1 + y2 * y2 + y3 * y3;
  __syncthreads();
  if (t < 128) {
    float2 pr;
    pr.x = sS1[t] + sS1[128 + t];
    pr.y = sS2[t] + sS2[128 + t];
    *(float2*)(lnpart + ((size_t)j * 128 + t) * 2) = pr;
  }
}

// ---------------------------------------------------------------------------
// K4: logits = LN(a) @ dpw + dpb with LN folded in:
//   logits[c] = inv*(a . pwgT[c]) - inv*mu*u[c] + w[c] + dpb[c]
// where pwgT[c][k] = g[k]*pw[k][c], uv = {u | w}. mu/inv from K3 partials.
// ---------------------------------------------------------------------------
__global__ __launch_bounds__(256) void pwln_k(
    const float* __restrict__ A, const float* __restrict__ WT,
    const float* __restrict__ lnpart, const float* __restrict__ uv,
    const float* __restrict__ dpb, float* __restrict__ L)
{
  __shared__ float2 sA2[32 * 131];
  __shared__ float2 sW2[8 * 34];
  __shared__ float sMu[128];
  __shared__ float sInv[128];
  const int j = blockIdx.x, t = threadIdx.x;
  const int n0 = j * 8;
  const int b = t & 127, half = t >> 7;
  if (t < 128) {
    float s1 = 0.f, s2 = 0.f;
    const float2* lp = (const float2*)lnpart;
    for (int jj = 0; jj < 64; ++jj) {
      float2 pr = lp[jj * 128 + t];
      s1 += pr.x; s2 += pr.y;
    }
    float mu = s1 * (1.f / 512.f);
    float var = s2 * (1.f / 512.f) - mu * mu;
    sMu[t] = mu;
    sInv[t] = 1.f / sqrtf(var + 1e-5f);
  }
  float a0 = 0.f, a1 = 0.f, a2 = 0.f, a3 = 0.f;
  for (int kt = 0; kt < 512; kt += 64) {
    stage_act2(A + kt, 512, sA2, t);
    if (t < 128) {
      int r = t >> 4, k4 = t & 15;
      float4 w = *(const float4*)(WT + (size_t)(n0 + r) * 512 + kt + k4 * 4);
      float2 p0; p0.x = w.x; p0.y = w.y;
      float2 p1; p1.x = w.z; p1.y = w.w;
      sW2[r * 34 + k4 * 2 + 0] = p0;
      sW2[r * 34 + k4 * 2 + 1] = p1;
    }
    __syncthreads();
    const float2* wr = sW2 + half * 136;
#pragma unroll 8
    for (int kk = 0; kk < 32; ++kk) {
      float2 a  = sA2[kk * 131 + b];
      float2 w0 = wr[kk];
      float2 w1 = wr[34 + kk];
      float2 w2 = wr[68 + kk];
      float2 w3 = wr[102 + kk];
      a0 += a.x * w0.x + a.y * w0.y;
      a1 += a.x * w1.x + a.y * w1.y;
      a2 += a.x * w2.x + a.y * w2.y;
      a3 += a.x * w3.x + a.y * w3.y;
    }
    __syncthreads();
  }
  int c0 = n0 + half * 4;
  float mu = sMu[b], inv = sInv[b];
  float4 o;
  o.x = inv * a0 - inv * mu * uv[c0 + 0] + uv[512 + c0 + 0] + dpb[c0 + 0];
  o.y = inv * a1 - inv * mu * uv[c0 + 1] + uv[512 + c0 + 1] + dpb[c0 + 1];
  o.z = inv * a2 - inv * mu * uv[c0 + 2] + uv[512 + c0 + 2] + dpb[c0 + 2];
  o.w = inv * a3 - inv * mu * uv[c0 + 3] + uv[512 + c0 + 3] + dpb[c0 + 3];
  *(float4*)(L + (size_t)b * 512 + c0) = o;
}

// ---------------------------------------------------------------------------
__global__ __launch_bounds__(256) void init_k(
    const float* __restrict__ emb, float* __restrict__ ctxh, float* __restrict__ cbuf,
    int* visited, int* ucount, int* complete, int* allvis, int* first, int* prev,
    float* out)
{
  int b = blockIdx.x, t = threadIdx.x;
#pragma unroll
  for (int r = 0; r < 2; ++r) {
    int e = t + 256 * r;
    float s = 0.f;
    for (int i = 0; i < Nn; ++i) s += emb[((size_t)b * Nn + i) * 512 + e];
    ctxh[(size_t)b * 1536 + e] = s / 100.f;
    ctxh[(size_t)b * 1536 + 512 + e] = 0.f;   // h slot0
    cbuf[(size_t)b * 512 + e] = 0.f;
  }
  if (t < Nn) visited[b * Nn + t] = 0;
  if (t == 0) {
    ucount[b] = 0; complete[b] = 0; allvis[b] = 0; first[b] = 0; prev[b] = 0;
    out[150 * Bb + b] = 0.f;
  }
}

// ---------------------------------------------------------------------------
// K5: resolve complete from done-partials, scores vs node_emb, bonus/mask,
// argmax + softmax logp, state update, ctx <- emb[curr].
// ---------------------------------------------------------------------------
__global__ __launch_bounds__(256) void select2_k(
    const float* __restrict__ L, const float* __restrict__ emb, const float* __restrict__ ew,
    const float* __restrict__ dpart, const float* __restrict__ done_b,
    int* visited, int* ucount, int* complete, int* allvis, int* first, int* prev,
    float* __restrict__ ctxh, float* __restrict__ out,
    const float* __restrict__ sb_p, const float* __restrict__ rp_p, int step)
{
  int b = blockIdx.x, t = threadIdx.x;
  __shared__ float lg[512];
  __shared__ float sc[128];
  __shared__ float red[256];
  __shared__ int redi[256];
  __shared__ int s_cm;
  red[t] = dpart[(size_t)b * 256 + t];
  lg[t] = L[(size_t)b * 512 + t];
  lg[t + 256] = L[(size_t)b * 512 + 256 + t];
  __syncthreads();
  for (int o = 128; o > 0; o >>= 1) { if (t < o) red[t] += red[t + o]; __syncthreads(); }
  if (t == 0) {
    int cm = complete[b];
    if (!cm && ucount[b] >= Nn && step >= Nn && (red[0] + done_b[0]) > 0.f) {
      cm = 1; complete[b] = 1;
    }
    s_cm = cm;
  }
  __syncthreads();
  if (t < Nn) {
    const float* er = emb + ((size_t)b * Nn + t) * 512;
    float s = 0.f;
#pragma unroll 8
    for (int e4 = 0; e4 < 128; ++e4) {
      float4 ev = *(const float4*)(er + e4 * 4);
      float4 lv = *(const float4*)(lg + e4 * 4);
      s += lv.x * ev.x + lv.y * ev.y + lv.z * ev.z + lv.w * ev.w;
    }
    int av = allvis[b];
    if (!av && visited[b * Nn + t]) s = rp_p[0];
    if (av) {
      int pv = prev[b];
      float direct = ew[(size_t)b * 10000 + (size_t)pv * 100];
      float via = ew[(size_t)b * 10000 + (size_t)pv * 100 + t] + ew[(size_t)b * 10000 + (size_t)t * 100];
      if (via < direct) s += sb_p[0] * (direct - via) / direct;
    }
    if (s_cm) s = (t == first[b]) ? 100.f : -1e9f;
    sc[t] = s;
  }
  __syncthreads();
  float vv = (t < Nn) ? sc[t] : -3.4e38f;
  int ii = (t < Nn) ? t : 0x7fffffff;
  red[t] = vv; redi[t] = ii;
  __syncthreads();
  for (int o = 128; o > 0; o >>= 1) {
    if (t < o) {
      float v2 = red[t + o]; int i2 = redi[t + o];
      if (v2 > red[t] || (v2 == red[t] && i2 < redi[t])) { red[t] = v2; redi[t] = i2; }
    }
    __syncthreads();
  }
  float m = red[0];
  int curr = redi[0];
  __syncthreads();
  float ex = (t < Nn) ? expf(sc[t] - m) : 0.f;
  red[t] = ex; __syncthreads();
  for (int o = 128; o > 0; o >>= 1) { if (t < o) red[t] += red[t + o]; __syncthreads(); }
  float Z = red[0];
  if (t == 0) {
    float pcur = expf(sc[curr] - m) / Z;
    out[step * Bb + b] = logf(pcur + 1e-10f);
    out[(151 + step) * Bb + b] = (float)curr;
    if (!s_cm) {
      if (!visited[b * Nn + curr]) ucount[b] = ucount[b] + 1;
      visited[b * Nn + curr] = 1;
    }
    if (ucount[b] >= Nn) allvis[b] = 1;
    if (step == 0) first[b] = curr;
    prev[b] = curr;
  }
  const float* src = emb + ((size_t)b * Nn + curr) * 512;
  ctxh[(size_t)b * 1536 + t] = src[t];
  ctxh[(size_t)b * 1536 + t + 256] = src[t + 256];
}

__global__ void final_k(const int* complete, const int* first, float* out)
{
  int b = threadIdx.x;
  out[(151 + 150) * Bb + b] = complete[b] ? 0.f : (float)first[b];
}

// ---------------------------------------------------------------------------
extern "C" void kernel_launch(void* const* d_in, const int* in_sizes, int n_in,
                              void* d_out, int out_size, void* d_ws, size_t ws_size,
                              hipStream_t stream)
{
  const float* nf      = (const float*)d_in[0];
  const float* ew      = (const float*)d_in[1];
  const float* pe      = (const float*)d_in[2];
  const float* in_w    = (const float*)d_in[3];
  const float* in_b    = (const float*)d_in[4];
  const float* enc_wq  = (const float*)d_in[5];
  const float* enc_wk  = (const float*)d_in[6];
  const float* enc_wv  = (const float*)d_in[7];
  const float* enc_wo  = (const float*)d_in[8];
  const float* enc_bq  = (const float*)d_in[9];
  const float* enc_bk  = (const float*)d_in[10];
  const float* enc_bv  = (const float*)d_in[11];
  const float* enc_bo  = (const float*)d_in[12];
  const float* enc_w1  = (const float*)d_in[13];
  const float* enc_b1  = (const float*)d_in[14];
  const float* enc_w2  = (const float*)d_in[15];
  const float* enc_b2  = (const float*)d_in[16];
  const float* ln1g    = (const float*)d_in[17];
  const float* ln1b    = (const float*)d_in[18];
  const float* ln2g    = (const float*)d_in[19];
  const float* ln2b    = (const float*)d_in[20];
  const float* wih     = (const float*)d_in[21];
  const float* whh     = (const float*)d_in[22];
  const float* bih     = (const float*)d_in[23];
  const float* bhh     = (const float*)d_in[24];
  const float* dwq     = (const float*)d_in[25];
  const float* dwk     = (const float*)d_in[26];
  const float* dwv     = (const float*)d_in[27];
  const float* dwo     = (const float*)d_in[28];
  const float* dpw     = (const float*)d_in[29];
  const float* dbq     = (const float*)d_in[30];
  const float* dbk     = (const float*)d_in[31];
  const float* dbv     = (const float*)d_in[32];
  const float* dbo     = (const float*)d_in[33];
  const float* dpb     = (const float*)d_in[34];
  const float* dlng    = (const float*)d_in[35];
  const float* dlnb    = (const float*)d_in[36];
  const float* sbp     = (const float*)d_in[37];
  const float* rpp     = (const float*)d_in[38];
  const float* done_w  = (const float*)d_in[39];
  const float* done_b  = (const float*)d_in[40];
  float* out = (float*)d_out;

  // ---- workspace carve ----
  const size_t SZ = 12800ull * 512;            // 6,553,600 elements
  float* ws = (float*)d_ws;
  float* x   = ws;                              // fp32 node emb
  float* xq  = x + SZ;                          // q / wo-out / ff2-out
  float* xk  = xq + SZ;                         // enc k -> dec K
  float* xv  = xk + SZ;                         // enc v -> FF2 partials -> dec V
  _Float16* xh = (_Float16*)(xv + SZ);          // x hi plane
  _Float16* xl = xh + SZ;                       // x lo plane
  _Float16* oh = xl + SZ;                       // attn-out hi  (alias: FF1-out hi)
  _Float16* ol = oh + SZ;                       // attn-out lo  (alias: FF1-out lo)
  _Float16* wb = ol + SZ;                       // weight planes, 6,291,456 f16
  _Float16* wqh = wb;               _Float16* wql = wqh + 262144;
  _Float16* wkh = wql + 262144;     _Float16* wkl = wkh + 262144;
  _Float16* wvh = wkl + 262144;     _Float16* wvl = wvh + 262144;
  _Float16* woh_ = wvl + 262144;    _Float16* wol_ = woh_ + 262144;
  _Float16* w1h = wol_ + 262144;    _Float16* w1l = w1h + 1048576;
  _Float16* w2h = w1l + 1048576;    _Float16* w2l = w2h + 1048576;
  // decode region (within old decode envelope)
  float* ctxh   = (float*)(w2l + 1048576);      // 128 x 1536 : ctx | hA | hB
  float* cbuf   = ctxh + 196608;                // 128 x 512
  float* dwqT   = cbuf + 65536;                 // 512 x 512
  float* dwoT   = dwqT + 262144;                // 512 x 512
  float* pwgT   = dwoT + 262144;                // 512 x 512 (g-scaled)
  float* uvv    = pwgT + 262144;                // 1024: {u | w}
  float* lnpart = uvv + 1024;                   // 64 x 128 x 2
  float* dpart  = lnpart + 16384;               // 128 x 256
  float* attno  = dpart + 32768;                // 128 x 512 dec-attn out
  float* woO    = attno + 65536;                // 128 x 512 wo out
  float* lgts   = woO + 65536;                  // 128 x 512 logits
  int* ivis     = (int*)(lgts + 65536);
  int* ucount   = ivis + 12800;
  int* complete = ucount + 128;
  int* allvis   = complete + 128;
  int* first    = allvis + 128;
  int* prev     = first + 128;

  // ---- encoder ----
  input_proj_k<<<25600, 256, 0, stream>>>(nf, in_w, in_b, pe, x, xh, xl);

  for (int l = 0; l < Ll; ++l) {
    const float* wq = enc_wq + (size_t)l * 262144;
    const float* wk = enc_wk + (size_t)l * 262144;
    const float* wv = enc_wv + (size_t)l * 262144;
    const float* wo = enc_wo + (size_t)l * 262144;
    const float* bq = enc_bq + (size_t)l * 512;
    const float* bk = enc_bk + (size_t)l * 512;
    const float* bv = enc_bv + (size_t)l * 512;
    const float* bo = enc_bo + (size_t)l * 512;
    const float* w1 = enc_w1 + (size_t)l * 1048576;
    const float* b1 = enc_b1 + (size_t)l * 2048;
    const float* w2 = enc_w2 + (size_t)l * 1048576;
    const float* b2 = enc_b2 + (size_t)l * 512;

    wconv_k<<<dim3(16, 16), 256, 0, stream>>>(wq, 512, 512, wqh, wql);
    wconv_k<<<dim3(16, 16), 256, 0, stream>>>(wk, 512, 512, wkh, wkl);
    wconv_k<<<dim3(16, 16), 256, 0, stream>>>(wv, 512, 512, wvh, wvl);
    wconv_k<<<dim3(16, 16), 256, 0, stream>>>(wo, 512, 512, woh_, wol_);
    wconv_k<<<dim3(64, 16), 256, 0, stream>>>(w1, 512, 2048, w1h, w1l);
    wconv_k<<<dim3(16, 64), 256, 0, stream>>>(w2, 2048, 512, w2h, w2l);

    mgemm_k<false, true, true, false><<<dim3(4, 100), 256, 0, stream>>>(
        xh, xl, 512, wqh, wql, 512, xq, nullptr, nullptr, 512, bq, 512, 0, 0);
    mgemm_k<false, true, true, false><<<dim3(4, 100), 256, 0, stream>>>(
        xh, xl, 512, wkh, wkl, 512, xk, nullptr, nullptr, 512, bk, 512, 0, 0);
    mgemm_k<false, true, true, false><<<dim3(4, 100), 256, 0, stream>>>(
        xh, xl, 512, wvh, wvl, 512, xv, nullptr, nullptr, 512, bv, 512, 0, 0);
    enc_attn_k<<<1024, 256, 0, stream>>>(xq, xk, xv, oh, ol);
    mgemm_k<false, true, true, false><<<dim3(4, 100), 256, 0, stream>>>(
        oh, ol, 512, woh_, wol_, 512, xq, nullptr, nullptr, 512, bo, 512, 0, 0);
    ln_k<<<12800, 256, 0, stream>>>(x, xq, ln1g + l * 512, ln1b + l * 512, x, xh, xl);
    for (int c = 0; c < 4; ++c) {
      mgemm_k<true, true, false, false><<<dim3(16, 25), 256, 0, stream>>>(
          xh + (size_t)c * 3200 * 512, xl + (size_t)c * 3200 * 512, 512,
          w1h, w1l, 512, nullptr, oh, ol, 2048, b1, 512, 0, 0);
      mgemm_k<false, false, true, true><<<dim3(4, 25, 4), 256, 0, stream>>>(
          oh, ol, 2048, w2h, w2l, 2048, xv, nullptr, nullptr, 512,
          nullptr, 2048, 512, 3200);
      reduce4_k<<<6400, 256, 0, stream>>>(xv, b2, xq + (size_t)c * 3200 * 512);
    }
    ln_k<<<12800, 256, 0, stream>>>(x, xq, ln2g + l * 512, ln2b + l * 512, x, xh, xl);
  }

  // ---- decode prep: K/V step-invariant ----
  wconv_k<<<dim3(16, 16), 256, 0, stream>>>(dwk, 512, 512, wqh, wql);
  wconv_k<<<dim3(16, 16), 256, 0, stream>>>(dwv, 512, 512, wkh, wkl);
  mgemm_k<false, true, true, false><<<dim3(4, 100), 256, 0, stream>>>(
      xh, xl, 512, wqh, wql, 512, xk, nullptr, nullptr, 512, dbk, 512, 0, 0);
  mgemm_k<false, true, true, false><<<dim3(4, 100), 256, 0, stream>>>(
      xh, xl, 512, wkh, wkl, 512, xv, nullptr, nullptr, 512, dbv, 512, 0, 0);

  // one-time decode weight transposes (wb region is dead after the mgemms above)
  float* WgT = (float*)wb;                      // 2048 x 1024 fp32 (fits in wb)
  tconv_k<<<dim3(64, 16), 256, 0, stream>>>(wih, 2048, nullptr, WgT, 1024, 0);
  tconv_k<<<dim3(64, 16), 256, 0, stream>>>(whh, 2048, nullptr, WgT, 1024, 512);
  tconv_k<<<dim3(16, 16), 256, 0, stream>>>(dwq, 512, nullptr, dwqT, 512, 0);
  tconv_k<<<dim3(16, 16), 256, 0, stream>>>(dwo, 512, nullptr, dwoT, 512, 0);
  tconv_k<<<dim3(16, 16), 256, 0, stream>>>(dpw, 512, dlng, pwgT, 512, 0);
  uv_k<<<2, 256, 0, stream>>>(dpw, dlng, dlnb, uvv);
  init_k<<<128, 256, 0, stream>>>(x, ctxh, cbuf, ivis, ucount, complete, allvis, first, prev, out);

  // ---- decode loop: 5 kernels/step ----
  for (int step = 0; step < STEPS; ++step) {
    int hin = step & 1;
    lstm_fused_k<<<256, 256, 0, stream>>>(WgT, bih, bhh, ctxh, cbuf, done_w, dpart, hin);
    qattn_k<<<dim3(8, 8), 256, 0, stream>>>(ctxh, dwqT, dbq, xk, xv, attno, hin);
    wo_k<<<64, 256, 0, stream>>>(attno, dwoT, dbo, woO, lnpart);
    pwln_k<<<64, 256, 0, stream>>>(woO, pwgT, lnpart, uvv, dpb, lgts);
    select2_k<<<128, 256, 0, stream>>>(lgts, x, ew, dpart, done_b, ivis, ucount, complete,
                                       allvis, first, prev, ctxh, out, sbp, rpp, step);
  }
  final_k<<<1, 128, 0, stream>>>(complete, first, out);
}

// Round 3
// 16522.734 us; speedup vs baseline: 1.8503x; 1.8127x over previous
//
#include <hip/hip_runtime.h>
#include <math.h>

#define Bb 128
#define Nn 100
#define Ee 512
#define Hh 8
#define DHd 64
#define FFf 2048
#define Ll 6
#define STEPS 150

typedef _Float16 h8 __attribute__((ext_vector_type(8)));
typedef _Float16 h4 __attribute__((ext_vector_type(4)));
typedef float f4 __attribute__((ext_vector_type(4)));

// ---------------------------------------------------------------------------
// Split-f16 MFMA GEMM.  C[M,N] = A[M,K] @ B[K,N] computed as
// Ah*Bh + Ah*Bl + Al*Bh with f16 hi/lo planes (pre-split inputs).
// A planes: [M][K] f16.  B planes: pre-transposed [N][K] f16.
// Tile 128x128, BK=32, 4 waves (2x2), each wave 4x4 frags of 16x16x32.
// OUTF32: fp32 (+bias,+relu).  else: write f16 hi/lo planes (+bias,+relu).
// SPLITK: blockIdx.z picks K-chunk kc, partial to C + z*Mtot*ldc, no bias.
// ---------------------------------------------------------------------------
template<bool RELU, bool BIAS, bool OUTF32, bool SPLITK>
__global__ __launch_bounds__(256) void mgemm_k(
    const _Float16* __restrict__ Ah, const _Float16* __restrict__ Al, int lda,
    const _Float16* __restrict__ Bh, const _Float16* __restrict__ Bl, int ldb,
    float* __restrict__ C, _Float16* __restrict__ Ch, _Float16* __restrict__ Cl,
    int ldc, const float* __restrict__ bias, int K, int kc, int Mtot)
{
  __shared__ _Float16 sm[4 * 5120];            // 4 planes of 128 x (32+8pad)
  _Float16* sAh = sm;
  _Float16* sAl = sm + 5120;
  _Float16* sBh = sm + 10240;
  _Float16* sBl = sm + 15360;
  const int tid = threadIdx.x;
  const int m0 = blockIdx.y * 128, n0 = blockIdx.x * 128;
  const int k0 = SPLITK ? blockIdx.z * kc : 0;
  const int kEnd = SPLITK ? k0 + kc : K;
  const int lane = tid & 63, wave = tid >> 6;
  const int wm = wave >> 1, wn = wave & 1;
  const int m16 = lane & 15, kg = lane >> 4;
  f4 acc[4][4];
#pragma unroll
  for (int i = 0; i < 4; ++i)
#pragma unroll
    for (int j = 0; j < 4; ++j) acc[i][j] = (f4)0.f;

  for (int kt = k0; kt < kEnd; kt += 32) {
#pragma unroll
    for (int it = 0; it < 2; ++it) {
      int idx = tid + it * 256;                // 512 (row,g) slots
      int row = idx >> 2, g = idx & 3;
      int lo_ = row * 40 + g * 8;
      size_t ga = (size_t)(m0 + row) * lda + kt + g * 8;
      size_t gb = (size_t)(n0 + row) * ldb + kt + g * 8;
      *(h8*)(sAh + lo_) = *(const h8*)(Ah + ga);
      *(h8*)(sAl + lo_) = *(const h8*)(Al + ga);
      *(h8*)(sBh + lo_) = *(const h8*)(Bh + gb);
      *(h8*)(sBl + lo_) = *(const h8*)(Bl + gb);
    }
    __syncthreads();
    h8 a_h[4], a_l[4], b_h[4], b_l[4];
#pragma unroll
    for (int i = 0; i < 4; ++i) {
      int ro = (wm * 64 + i * 16 + m16) * 40 + kg * 8;
      int co = (wn * 64 + i * 16 + m16) * 40 + kg * 8;
      a_h[i] = *(const h8*)(sAh + ro);
      a_l[i] = *(const h8*)(sAl + ro);
      b_h[i] = *(const h8*)(sBh + co);
      b_l[i] = *(const h8*)(sBl + co);
    }
#pragma unroll
    for (int i = 0; i < 4; ++i)
#pragma unroll
      for (int j = 0; j < 4; ++j) {
        acc[i][j] = __builtin_amdgcn_mfma_f32_16x16x32_f16(a_h[i], b_h[j], acc[i][j], 0, 0, 0);
        acc[i][j] = __builtin_amdgcn_mfma_f32_16x16x32_f16(a_h[i], b_l[j], acc[i][j], 0, 0, 0);
        acc[i][j] = __builtin_amdgcn_mfma_f32_16x16x32_f16(a_l[i], b_h[j], acc[i][j], 0, 0, 0);
      }
    __syncthreads();
  }

  float* Cz = OUTF32 ? (C + (SPLITK ? (size_t)blockIdx.z * (size_t)Mtot * ldc : (size_t)0)) : C;
  int rb = m0 + wm * 64 + kg * 4;              // C/D: row=(lane>>4)*4+reg
  int cb = n0 + wn * 64 + m16;                 //      col=lane&15
#pragma unroll
  for (int j = 0; j < 4; ++j) {
    int col = cb + j * 16;
    float bv = BIAS ? bias[col] : 0.f;
#pragma unroll
    for (int i = 0; i < 4; ++i) {
#pragma unroll
      for (int r = 0; r < 4; ++r) {
        float v = acc[i][j][r] + bv;
        if (RELU) v = fmaxf(v, 0.f);
        int row = rb + i * 16 + r;
        if (OUTF32) {
          Cz[(size_t)row * ldc + col] = v;
        } else {
          _Float16 hh = (_Float16)v;
          Ch[(size_t)row * ldc + col] = hh;
          Cl[(size_t)row * ldc + col] = (_Float16)(v - (float)hh);
        }
      }
    }
  }
}

// ---------------------------------------------------------------------------
// Weight transpose + split:  W [K][N] fp32  ->  Th/Tl [N][K] f16
// ---------------------------------------------------------------------------
__global__ __launch_bounds__(256) void wconv_k(
    const float* __restrict__ W, int K, int N,
    _Float16* __restrict__ Th, _Float16* __restrict__ Tl)
{
  __shared__ float t[32][33];
  int n0 = blockIdx.x * 32, k0 = blockIdx.y * 32;
  int tid = threadIdx.x;
  int r = tid >> 3, c4 = (tid & 7) * 4;
  float4 v = *(const float4*)(W + (size_t)(k0 + r) * N + n0 + c4);
  t[r][c4 + 0] = v.x; t[r][c4 + 1] = v.y; t[r][c4 + 2] = v.z; t[r][c4 + 3] = v.w;
  __syncthreads();
  h4 hi, lo;
#pragma unroll
  for (int i = 0; i < 4; ++i) {
    float x = t[c4 + i][r];
    _Float16 hh = (_Float16)x;
    hi[i] = hh;
    lo[i] = (_Float16)(x - (float)hh);
  }
  *(h4*)(Th + (size_t)(n0 + r) * K + k0 + c4) = hi;
  *(h4*)(Tl + (size_t)(n0 + r) * K + k0 + c4) = lo;
}

// FF2 split-K(4) partial reduce + bias, chunk of 3200x512
__global__ __launch_bounds__(256) void reduce4_k(
    const float* __restrict__ P, const float* __restrict__ bias, float* __restrict__ out)
{
  int idx = blockIdx.x * 256 + threadIdx.x;   // < 3200*512
  const size_t S = 3200ull * 512;
  float v = P[idx] + P[idx + S] + P[idx + 2 * S] + P[idx + 3 * S] + bias[idx & 511];
  out[idx] = v;
}

// ---------------------------------------------------------------------------
// x = node_features @ in_w + in_b + pe   (+ f16 hi/lo planes)
// ---------------------------------------------------------------------------
__global__ __launch_bounds__(256) void input_proj_k(
    const float* __restrict__ nf, const float* __restrict__ inw,
    const float* __restrict__ inb, const float* __restrict__ pe,
    float* __restrict__ x, _Float16* __restrict__ xh, _Float16* __restrict__ xl)
{
  int idx = blockIdx.x * 256 + threadIdx.x;   // < 12800*512
  int bn = idx >> 9, e = idx & 511;
  int n = bn - (bn / Nn) * Nn;
  const float* fr = nf + (size_t)bn * 8;
  float s = inb[e] + pe[(size_t)n * 512 + e];
#pragma unroll
  for (int i = 0; i < 8; ++i) s += fr[i] * inw[(size_t)i * 512 + e];
  x[idx] = s;
  _Float16 hh = (_Float16)s;
  xh[idx] = hh;
  xl[idx] = (_Float16)(s - (float)hh);
}

// ---------------------------------------------------------------------------
// Residual + LayerNorm (rows of 512) + f16 hi/lo planes
// ---------------------------------------------------------------------------
__global__ __launch_bounds__(256) void ln_k(
    const float* __restrict__ xin, const float* __restrict__ yin,
    const float* __restrict__ g, const float* __restrict__ bb,
    float* __restrict__ out, _Float16* __restrict__ oh, _Float16* __restrict__ ol)
{
  int row = blockIdx.x, t = threadIdx.x;
  __shared__ float red[256];
  size_t base = (size_t)row * 512;
  float v0 = xin[base + t] + yin[base + t];
  float v1 = xin[base + 256 + t] + yin[base + 256 + t];
  red[t] = v0 + v1;
  __syncthreads();
  for (int o = 128; o > 0; o >>= 1) { if (t < o) red[t] += red[t + o]; __syncthreads(); }
  float mu = red[0] * (1.f / 512.f);
  __syncthreads();
  float d0 = v0 - mu, d1 = v1 - mu;
  red[t] = d0 * d0 + d1 * d1;
  __syncthreads();
  for (int o = 128; o > 0; o >>= 1) { if (t < o) red[t] += red[t + o]; __syncthreads(); }
  float inv = 1.f / sqrtf(red[0] * (1.f / 512.f) + 1e-5f);
  float y0 = d0 * inv * g[t] + bb[t];
  float y1 = d1 * inv * g[t + 256] + bb[t + 256];
  out[base + t] = y0;
  out[base + 256 + t] = y1;
  _Float16 h0 = (_Float16)y0, h1 = (_Float16)y1;
  oh[base + t] = h0;           ol[base + t] = (_Float16)(y0 - (float)h0);
  oh[base + 256 + t] = h1;     ol[base + 256 + t] = (_Float16)(y1 - (float)h1);
}

// ---------------------------------------------------------------------------
// Fused encoder attention per (b,h); output written as f16 hi/lo planes.
// ---------------------------------------------------------------------------
__global__ __launch_bounds__(256) void enc_attn_k(
    const float* __restrict__ q, const float* __restrict__ k,
    const float* __restrict__ v, _Float16* __restrict__ oh, _Float16* __restrict__ ol)
{
  __shared__ __align__(16) float smem[14848];
  int bh = blockIdx.x; int b = bh >> 3, h = bh & 7;
  int t = threadIdx.x;
  float* qs = smem;           // stride 68
  float* kT = smem + 7616;    // stride 113
  float* p  = smem;           // stride 104 (overlay after phase 1)
  const float* qg = q + ((size_t)b * Nn) * 512 + h * 64;
  const float* kg = k + ((size_t)b * Nn) * 512 + h * 64;
  const float* vg = v + ((size_t)b * Nn) * 512 + h * 64;
  for (int idx = t; idx < 6400; idx += 256) {
    int i = idx >> 6, d = idx & 63;
    qs[i * 68 + d]  = qg[(size_t)i * 512 + d];
    kT[d * 113 + i] = kg[(size_t)i * 512 + d];
  }
  __syncthreads();
  int ti = t >> 4, tj = t & 15;
  int i0 = ti * 7, j0 = tj * 7;
  float s[7][7];
#pragma unroll
  for (int r = 0; r < 7; ++r)
#pragma unroll
    for (int c = 0; c < 7; ++c) s[r][c] = 0.f;
  for (int kk = 0; kk < 64; ++kk) {
    float a[7], bb[7];
#pragma unroll
    for (int r = 0; r < 7; ++r) a[r] = qs[(i0 + r) * 68 + kk];
#pragma unroll
    for (int c = 0; c < 7; ++c) bb[c] = kT[kk * 113 + j0 + c];
#pragma unroll
    for (int r = 0; r < 7; ++r)
#pragma unroll
      for (int c = 0; c < 7; ++c) s[r][c] += a[r] * bb[c];
  }
  __syncthreads();
#pragma unroll
  for (int r = 0; r < 7; ++r)
#pragma unroll
    for (int c = 0; c < 7; ++c) {
      int i = i0 + r, j = j0 + c;
      if (i < Nn && j < Nn) p[i * 104 + j] = s[r][c] * 0.125f;
    }
  __syncthreads();
  int w = t >> 6, lane = t & 63;
  for (int i = w; i < Nn; i += 4) {
    float x0 = p[i * 104 + lane];
    float x1 = (lane < 36) ? p[i * 104 + 64 + lane] : -3.4e38f;
    float mx = fmaxf(x0, x1);
    for (int msk = 32; msk; msk >>= 1) mx = fmaxf(mx, __shfl_xor(mx, msk));
    float e0 = expf(x0 - mx);
    float e1 = (lane < 36) ? expf(x1 - mx) : 0.f;
    float ss = e0 + e1;
    for (int msk = 32; msk; msk >>= 1) ss += __shfl_xor(ss, msk);
    p[i * 104 + lane] = e0 / ss;
    if (lane < 36) p[i * 104 + 64 + lane] = e1 / ss;
  }
  __syncthreads();
  int d0 = tj * 4;
  float oa[7][4];
#pragma unroll
  for (int r = 0; r < 7; ++r)
#pragma unroll
    for (int c = 0; c < 4; ++c) oa[r][c] = 0.f;
  for (int j = 0; j < Nn; ++j) {
    float pr[7];
#pragma unroll
    for (int r = 0; r < 7; ++r) pr[r] = p[(i0 + r) * 104 + j];
    float4 vv = *(const float4*)(vg + (size_t)j * 512 + d0);
#pragma unroll
    for (int r = 0; r < 7; ++r) {
      oa[r][0] += pr[r] * vv.x; oa[r][1] += pr[r] * vv.y;
      oa[r][2] += pr[r] * vv.z; oa[r][3] += pr[r] * vv.w;
    }
  }
  size_t ob = ((size_t)b * Nn) * 512 + h * 64 + d0;
#pragma unroll
  for (int r = 0; r < 7; ++r)
    if (i0 + r < Nn) {
      h4 hv, lv;
#pragma unroll
      for (int c = 0; c < 4; ++c) {
        _Float16 hh = (_Float16)oa[r][c];
        hv[c] = hh;
        lv[c] = (_Float16)(oa[r][c] - (float)hh);
      }
      *(h4*)(oh + ob + (size_t)(i0 + r) * 512) = hv;
      *(h4*)(ol + ob + (size_t)(i0 + r) * 512) = lv;
    }
}

// ---------------------------------------------------------------------------
// fp32 tiled GEMM (decode-loop small GEMMs only; split-K partials)
// ---------------------------------------------------------------------------
template<int BM, int BN, int BK, int TM, int TN>
__global__ __launch_bounds__(256) void gemm_k(
    const float* __restrict__ A, int lda,
    const float* __restrict__ B1, const float* __restrict__ B2, int splitB, int ldb,
    float* __restrict__ C, int ldc, int M, int N, int K, int kChunk)
{
  __shared__ __align__(16) float As[BK][BM + 4];
  __shared__ __align__(16) float Bs[BK][BN + 4];
  const int tid = threadIdx.x;
  const int m0 = blockIdx.y * BM;
  const int n0 = blockIdx.x * BN;
  const int k0 = blockIdx.z * kChunk;
  const int kEnd = k0 + kChunk;
  constexpr int TCOLS = BN / TN;
  const int tm = tid / TCOLS;
  const int tn = tid % TCOLS;
  float acc[TM][TN];
#pragma unroll
  for (int i = 0; i < TM; ++i)
#pragma unroll
    for (int j = 0; j < TN; ++j) acc[i][j] = 0.f;

  for (int kt = k0; kt < kEnd; kt += BK) {
    constexpr int A4 = BM * BK / 4;
    for (int c = tid; c < A4; c += 256) {
      int mm = c / (BK / 4);
      int k4 = (c % (BK / 4)) * 4;
      float4 av = *(const float4*)(A + (size_t)(m0 + mm) * lda + kt + k4);
      As[k4 + 0][mm] = av.x;
      As[k4 + 1][mm] = av.y;
      As[k4 + 2][mm] = av.z;
      As[k4 + 3][mm] = av.w;
    }
    constexpr int B4 = BK * BN / 4;
    for (int c = tid; c < B4; c += 256) {
      int kk = c / (BN / 4);
      int n4 = (c % (BN / 4)) * 4;
      int kgi = kt + kk;
      const float* Brow = (kgi < splitB) ? (B1 + (size_t)kgi * ldb)
                                         : (B2 + (size_t)(kgi - splitB) * ldb);
      *(float4*)&Bs[kk][n4] = *(const float4*)(Brow + n0 + n4);
    }
    __syncthreads();
#pragma unroll
    for (int kk = 0; kk < BK; ++kk) {
      float a[TM], b[TN];
#pragma unroll
      for (int i = 0; i < TM; ++i) a[i] = As[kk][tm * TM + i];
#pragma unroll
      for (int j = 0; j < TN; ++j) b[j] = Bs[kk][tn * TN + j];
#pragma unroll
      for (int i = 0; i < TM; ++i)
#pragma unroll
        for (int j = 0; j < TN; ++j)
          acc[i][j] += a[i] * b[j];
    }
    __syncthreads();
  }

  float* Cout = C + (size_t)blockIdx.z * (size_t)M * ldc;
#pragma unroll
  for (int i = 0; i < TM; ++i) {
    int m = m0 + tm * TM + i;
#pragma unroll
    for (int j = 0; j < TN; j += 4) {
      int n = n0 + tn * TN + j;
      float4 r;
      r.x = acc[i][j + 0]; r.y = acc[i][j + 1]; r.z = acc[i][j + 2]; r.w = acc[i][j + 3];
      *(float4*)(Cout + (size_t)m * ldc + n) = r;
    }
  }
}

// ---------------------------------------------------------------------------
__global__ __launch_bounds__(256) void init_k(
    const float* __restrict__ emb, float* __restrict__ ctxh, float* __restrict__ cbuf,
    int* visited, int* ucount, int* complete, int* allvis, int* first, int* prev,
    float* out)
{
  int b = blockIdx.x, t = threadIdx.x;
#pragma unroll
  for (int r = 0; r < 2; ++r) {
    int e = t + 256 * r;
    float s = 0.f;
    for (int i = 0; i < Nn; ++i) s += emb[((size_t)b * Nn + i) * 512 + e];
    ctxh[(size_t)b * 1024 + e] = s / 100.f;
    ctxh[(size_t)b * 1024 + 512 + e] = 0.f;
    cbuf[(size_t)b * 512 + e] = 0.f;
  }
  if (t < Nn) visited[b * Nn + t] = 0;
  if (t == 0) {
    ucount[b] = 0; complete[b] = 0; allvis[b] = 0; first[b] = 0; prev[b] = 0;
    out[150 * Bb + b] = 0.f;
  }
}

__device__ __forceinline__ float sigm(float x) { return 1.f / (1.f + expf(-x)); }

__global__ __launch_bounds__(256) void lstm_pw_k(
    const float* __restrict__ gP, const float* __restrict__ bih, const float* __restrict__ bhh,
    float* __restrict__ ctxh, float* __restrict__ cbuf,
    const float* __restrict__ done_w, const float* __restrict__ done_b,
    int* complete, const int* ucount, int step)
{
  int b = blockIdx.x, t = threadIdx.x;
  __shared__ float red[256];
  const float* g0 = gP + (size_t)b * 2048;
  const float* g1 = gP + 262144 + (size_t)b * 2048;
  float dsum = 0.f;
#pragma unroll
  for (int r = 0; r < 2; ++r) {
    int e = t + 256 * r;
    float ig = g0[e] + g1[e] + bih[e] + bhh[e];
    float fg = g0[e + 512] + g1[e + 512] + bih[e + 512] + bhh[e + 512];
    float gg = g0[e + 1024] + g1[e + 1024] + bih[e + 1024] + bhh[e + 1024];
    float og = g0[e + 1536] + g1[e + 1536] + bih[e + 1536] + bhh[e + 1536];
    float cprev = cbuf[(size_t)b * 512 + e];
    float c2 = sigm(fg) * cprev + sigm(ig) * tanhf(gg);
    float h2 = sigm(og) * tanhf(c2);
    cbuf[(size_t)b * 512 + e] = c2;
    ctxh[(size_t)b * 1024 + 512 + e] = h2;
    dsum += h2 * done_w[e];
  }
  red[t] = dsum; __syncthreads();
  for (int o = 128; o > 0; o >>= 1) { if (t < o) red[t] += red[t + o]; __syncthreads(); }
  if (t == 0) {
    float z = red[0] + done_b[0];
    if (!complete[b] && ucount[b] >= Nn && step >= Nn && z > 0.f) complete[b] = 1;
  }
}

__global__ __launch_bounds__(128) void dec_attn_k(
    const float* __restrict__ qP, const float* __restrict__ bq,
    const float* __restrict__ Kd, const float* __restrict__ Vd,
    float* __restrict__ o)
{
  int bh = blockIdx.x; int b = bh >> 3, h = bh & 7;
  int t = threadIdx.x;
  __shared__ float qh[64];
  __shared__ float p[100];
  __shared__ float red[128];
  if (t < 64) {
    float s = bq[h * 64 + t];
#pragma unroll
    for (int s8 = 0; s8 < 8; ++s8) s += qP[(size_t)s8 * 65536 + (size_t)b * 512 + h * 64 + t];
    qh[t] = s;
  }
  __syncthreads();
  float scv = -3.4e38f;
  if (t < Nn) {
    const float* kr = Kd + ((size_t)b * Nn + t) * 512 + h * 64;
    float s = 0.f;
#pragma unroll
    for (int d = 0; d < 64; ++d) s += qh[d] * kr[d];
    scv = s * 0.125f;
  }
  red[t] = scv; __syncthreads();
  for (int o2 = 64; o2 > 0; o2 >>= 1) { if (t < o2) red[t] = fmaxf(red[t], red[t + o2]); __syncthreads(); }
  float m = red[0]; __syncthreads();
  float ex = (t < Nn) ? expf(scv - m) : 0.f;
  red[t] = ex; __syncthreads();
  for (int o2 = 64; o2 > 0; o2 >>= 1) { if (t < o2) red[t] += red[t + o2]; __syncthreads(); }
  float Z = red[0];
  if (t < Nn) p[t] = ex / Z;
  __syncthreads();
  if (t < 64) {
    float acc = 0.f;
    const float* vr = Vd + (size_t)b * Nn * 512 + h * 64 + t;
    for (int j = 0; j < Nn; ++j) acc += p[j] * vr[(size_t)j * 512];
    o[(size_t)b * 512 + h * 64 + t] = acc;
  }
}

__global__ __launch_bounds__(256) void dec_ln_k(
    const float* __restrict__ woP, const float* __restrict__ bo,
    const float* __restrict__ g, const float* __restrict__ bb,
    float* __restrict__ out)
{
  int b = blockIdx.x, t = threadIdx.x;
  __shared__ float red[256];
  float v[2];
#pragma unroll
  for (int r = 0; r < 2; ++r) {
    int e = t + 256 * r;
    float s = bo[e];
#pragma unroll
    for (int s8 = 0; s8 < 8; ++s8) s += woP[(size_t)s8 * 65536 + (size_t)b * 512 + e];
    v[r] = s;
  }
  red[t] = v[0] + v[1]; __syncthreads();
  for (int o = 128; o > 0; o >>= 1) { if (t < o) red[t] += red[t + o]; __syncthreads(); }
  float mu = red[0] * (1.f / 512.f);
  __syncthreads();
  float d0 = v[0] - mu, d1 = v[1] - mu;
  red[t] = d0 * d0 + d1 * d1; __syncthreads();
  for (int o = 128; o > 0; o >>= 1) { if (t < o) red[t] += red[t + o]; __syncthreads(); }
  float inv = 1.f / sqrtf(red[0] * (1.f / 512.f) + 1e-5f);
  out[(size_t)b * 512 + t] = d0 * inv * g[t] + bb[t];
  out[(size_t)b * 512 + t + 256] = d1 * inv * g[t + 256] + bb[t + 256];
}

__global__ __launch_bounds__(256) void select_k(
    const float* __restrict__ pwP, const float* __restrict__ pb,
    const float* __restrict__ emb, const float* __restrict__ ew,
    int* visited, int* ucount, int* complete, int* allvis, int* first, int* prev,
    float* __restrict__ ctxh, float* __restrict__ out,
    const float* __restrict__ sb_p, const float* __restrict__ rp_p, int step)
{
  int b = blockIdx.x, t = threadIdx.x;
  __shared__ float logits[512];
  __shared__ float sc[128];
  __shared__ float red[256];
  __shared__ int redi[256];
#pragma unroll
  for (int r = 0; r < 2; ++r) {
    int e = t + 256 * r;
    float s = pb[e];
#pragma unroll
    for (int s8 = 0; s8 < 8; ++s8) s += pwP[(size_t)s8 * 65536 + (size_t)b * 512 + e];
    logits[e] = s;
  }
  __syncthreads();
  if (t < Nn) {
    const float* er = emb + ((size_t)b * Nn + t) * 512;
    float s = 0.f;
    for (int e = 0; e < 512; ++e) s += logits[e] * er[e];
    int av = allvis[b];
    if (!av && visited[b * Nn + t]) s = rp_p[0];
    if (av) {
      int pv = prev[b];
      float direct = ew[(size_t)b * 10000 + (size_t)pv * 100];
      float via = ew[(size_t)b * 10000 + (size_t)pv * 100 + t] + ew[(size_t)b * 10000 + (size_t)t * 100];
      if (via < direct) s += sb_p[0] * (direct - via) / direct;
    }
    if (complete[b]) s = (t == first[b]) ? 100.f : -1e9f;
    sc[t] = s;
  }
  __syncthreads();
  float vv = (t < Nn) ? sc[t] : -3.4e38f;
  int ii = (t < Nn) ? t : 0x7fffffff;
  red[t] = vv; redi[t] = ii;
  __syncthreads();
  for (int o = 128; o > 0; o >>= 1) {
    if (t < o) {
      float v2 = red[t + o]; int i2 = redi[t + o];
      if (v2 > red[t] || (v2 == red[t] && i2 < redi[t])) { red[t] = v2; redi[t] = i2; }
    }
    __syncthreads();
  }
  float m = red[0];
  int curr = redi[0];
  __syncthreads();
  float ex = (t < Nn) ? expf(sc[t] - m) : 0.f;
  red[t] = ex; __syncthreads();
  for (int o = 128; o > 0; o >>= 1) { if (t < o) red[t] += red[t + o]; __syncthreads(); }
  float Z = red[0];
  if (t == 0) {
    float pcur = expf(sc[curr] - m) / Z;
    out[step * Bb + b] = logf(pcur + 1e-10f);
    out[(151 + step) * Bb + b] = (float)curr;
    if (!complete[b]) {
      if (!visited[b * Nn + curr]) ucount[b] = ucount[b] + 1;
      visited[b * Nn + curr] = 1;
    }
    if (ucount[b] >= Nn) allvis[b] = 1;
    if (step == 0) first[b] = curr;
    prev[b] = curr;
  }
  const float* src = emb + ((size_t)b * Nn + curr) * 512;
  ctxh[(size_t)b * 1024 + t] = src[t];
  ctxh[(size_t)b * 1024 + t + 256] = src[t + 256];
}

__global__ void final_k(const int* complete, const int* first, float* out)
{
  int b = threadIdx.x;
  out[(151 + 150) * Bb + b] = complete[b] ? 0.f : (float)first[b];
}

// ---------------------------------------------------------------------------
extern "C" void kernel_launch(void* const* d_in, const int* in_sizes, int n_in,
                              void* d_out, int out_size, void* d_ws, size_t ws_size,
                              hipStream_t stream)
{
  const float* nf      = (const float*)d_in[0];
  const float* ew      = (const float*)d_in[1];
  const float* pe      = (const float*)d_in[2];
  const float* in_w    = (const float*)d_in[3];
  const float* in_b    = (const float*)d_in[4];
  const float* enc_wq  = (const float*)d_in[5];
  const float* enc_wk  = (const float*)d_in[6];
  const float* enc_wv  = (const float*)d_in[7];
  const float* enc_wo  = (const float*)d_in[8];
  const float* enc_bq  = (const float*)d_in[9];
  const float* enc_bk  = (const float*)d_in[10];
  const float* enc_bv  = (const float*)d_in[11];
  const float* enc_bo  = (const float*)d_in[12];
  const float* enc_w1  = (const float*)d_in[13];
  const float* enc_b1  = (const float*)d_in[14];
  const float* enc_w2  = (const float*)d_in[15];
  const float* enc_b2  = (const float*)d_in[16];
  const float* ln1g    = (const float*)d_in[17];
  const float* ln1b    = (const float*)d_in[18];
  const float* ln2g    = (const float*)d_in[19];
  const float* ln2b    = (const float*)d_in[20];
  const float* wih     = (const float*)d_in[21];
  const float* whh     = (const float*)d_in[22];
  const float* bih     = (const float*)d_in[23];
  const float* bhh     = (const float*)d_in[24];
  const float* dwq     = (const float*)d_in[25];
  const float* dwk     = (const float*)d_in[26];
  const float* dwv     = (const float*)d_in[27];
  const float* dwo     = (const float*)d_in[28];
  const float* dpw     = (const float*)d_in[29];
  const float* dbq     = (const float*)d_in[30];
  const float* dbk     = (const float*)d_in[31];
  const float* dbv     = (const float*)d_in[32];
  const float* dbo     = (const float*)d_in[33];
  const float* dpb     = (const float*)d_in[34];
  const float* dlng    = (const float*)d_in[35];
  const float* dlnb    = (const float*)d_in[36];
  const float* sbp     = (const float*)d_in[37];
  const float* rpp     = (const float*)d_in[38];
  const float* done_w  = (const float*)d_in[39];
  const float* done_b  = (const float*)d_in[40];
  float* out = (float*)d_out;

  // ---- workspace carve ----
  const size_t SZ = 12800ull * 512;            // 6,553,600 elements
  float* ws = (float*)d_ws;
  float* x   = ws;                              // fp32 node emb
  float* xq  = x + SZ;                          // q / wo-out / ff2-out
  float* xk  = xq + SZ;                         // enc k -> dec K
  float* xv  = xk + SZ;                         // enc v -> FF2 partials -> dec V
  _Float16* xh = (_Float16*)(xv + SZ);          // x hi plane
  _Float16* xl = xh + SZ;                       // x lo plane
  _Float16* oh = xl + SZ;                       // attn-out hi  (alias: FF1-out hi)
  _Float16* ol = oh + SZ;                       // attn-out lo  (alias: FF1-out lo)
  _Float16* wb = ol + SZ;                       // weight planes, 6,291,456 f16
  _Float16* wqh = wb;               _Float16* wql = wqh + 262144;
  _Float16* wkh = wql + 262144;     _Float16* wkl = wkh + 262144;
  _Float16* wvh = wkl + 262144;     _Float16* wvl = wvh + 262144;
  _Float16* woh_ = wvl + 262144;    _Float16* wol_ = woh_ + 262144;
  _Float16* w1h = wol_ + 262144;    _Float16* w1l = w1h + 1048576;
  _Float16* w2h = w1l + 1048576;    _Float16* w2l = w2h + 1048576;
  float* ctxh   = (float*)(w2l + 1048576);      // 128 x 1024 [ctx | h]
  float* cbuf   = ctxh + 131072;                // 128 x 512
  float* gatesP = cbuf + 65536;                 // 2 x 128 x 2048
  float* qP     = gatesP + 524288;              // 8 x 128 x 512
  float* woP    = qP + 524288;
  float* pwP    = woP + 524288;
  float* abuf   = pwP + 524288;                 // 128 x 512
  float* dbuf   = abuf + 65536;                 // 128 x 512 dec-attn out
  int* ivis     = (int*)(dbuf + 65536);
  int* ucount   = ivis + 12800;
  int* complete = ucount + 128;
  int* allvis   = complete + 128;
  int* first    = allvis + 128;
  int* prev     = first + 128;

  // ---- encoder ----
  input_proj_k<<<25600, 256, 0, stream>>>(nf, in_w, in_b, pe, x, xh, xl);

  for (int l = 0; l < Ll; ++l) {
    const float* wq = enc_wq + (size_t)l * 262144;
    const float* wk = enc_wk + (size_t)l * 262144;
    const float* wv = enc_wv + (size_t)l * 262144;
    const float* wo = enc_wo + (size_t)l * 262144;
    const float* bq = enc_bq + (size_t)l * 512;
    const float* bk = enc_bk + (size_t)l * 512;
    const float* bv = enc_bv + (size_t)l * 512;
    const float* bo = enc_bo + (size_t)l * 512;
    const float* w1 = enc_w1 + (size_t)l * 1048576;
    const float* b1 = enc_b1 + (size_t)l * 2048;
    const float* w2 = enc_w2 + (size_t)l * 1048576;
    const float* b2 = enc_b2 + (size_t)l * 512;

    wconv_k<<<dim3(16, 16), 256, 0, stream>>>(wq, 512, 512, wqh, wql);
    wconv_k<<<dim3(16, 16), 256, 0, stream>>>(wk, 512, 512, wkh, wkl);
    wconv_k<<<dim3(16, 16), 256, 0, stream>>>(wv, 512, 512, wvh, wvl);
    wconv_k<<<dim3(16, 16), 256, 0, stream>>>(wo, 512, 512, woh_, wol_);
    wconv_k<<<dim3(64, 16), 256, 0, stream>>>(w1, 512, 2048, w1h, w1l);
    wconv_k<<<dim3(16, 64), 256, 0, stream>>>(w2, 2048, 512, w2h, w2l);

    mgemm_k<false, true, true, false><<<dim3(4, 100), 256, 0, stream>>>(
        xh, xl, 512, wqh, wql, 512, xq, nullptr, nullptr, 512, bq, 512, 0, 0);
    mgemm_k<false, true, true, false><<<dim3(4, 100), 256, 0, stream>>>(
        xh, xl, 512, wkh, wkl, 512, xk, nullptr, nullptr, 512, bk, 512, 0, 0);
    mgemm_k<false, true, true, false><<<dim3(4, 100), 256, 0, stream>>>(
        xh, xl, 512, wvh, wvl, 512, xv, nullptr, nullptr, 512, bv, 512, 0, 0);
    enc_attn_k<<<1024, 256, 0, stream>>>(xq, xk, xv, oh, ol);
    mgemm_k<false, true, true, false><<<dim3(4, 100), 256, 0, stream>>>(
        oh, ol, 512, woh_, wol_, 512, xq, nullptr, nullptr, 512, bo, 512, 0, 0);
    ln_k<<<12800, 256, 0, stream>>>(x, xq, ln1g + l * 512, ln1b + l * 512, x, xh, xl);
    for (int c = 0; c < 4; ++c) {
      mgemm_k<true, true, false, false><<<dim3(16, 25), 256, 0, stream>>>(
          xh + (size_t)c * 3200 * 512, xl + (size_t)c * 3200 * 512, 512,
          w1h, w1l, 512, nullptr, oh, ol, 2048, b1, 512, 0, 0);
      mgemm_k<false, false, true, true><<<dim3(4, 25, 4), 256, 0, stream>>>(
          oh, ol, 2048, w2h, w2l, 2048, xv, nullptr, nullptr, 512,
          nullptr, 2048, 512, 3200);
      reduce4_k<<<6400, 256, 0, stream>>>(xv, b2, xq + (size_t)c * 3200 * 512);
    }
    ln_k<<<12800, 256, 0, stream>>>(x, xq, ln2g + l * 512, ln2b + l * 512, x, xh, xl);
  }

  // ---- decode prep: K/V step-invariant ----
  wconv_k<<<dim3(16, 16), 256, 0, stream>>>(dwk, 512, 512, wqh, wql);
  wconv_k<<<dim3(16, 16), 256, 0, stream>>>(dwv, 512, 512, wkh, wkl);
  mgemm_k<false, true, true, false><<<dim3(4, 100), 256, 0, stream>>>(
      xh, xl, 512, wqh, wql, 512, xk, nullptr, nullptr, 512, dbk, 512, 0, 0);
  mgemm_k<false, true, true, false><<<dim3(4, 100), 256, 0, stream>>>(
      xh, xl, 512, wkh, wkl, 512, xv, nullptr, nullptr, 512, dbv, 512, 0, 0);
  init_k<<<128, 256, 0, stream>>>(x, ctxh, cbuf, ivis, ucount, complete, allvis, first, prev, out);

  // ---- decode loop ----
  for (int step = 0; step < STEPS; ++step) {
    gemm_k<32, 64, 16, 2, 4><<<dim3(32, 4, 2), 256, 0, stream>>>(
        ctxh, 1024, wih, whh, 512, 2048, gatesP, 2048, 128, 2048, 1024, 512);
    lstm_pw_k<<<128, 256, 0, stream>>>(gatesP, bih, bhh, ctxh, cbuf, done_w, done_b,
                                       complete, ucount, step);
    gemm_k<32, 64, 16, 2, 4><<<dim3(8, 4, 8), 256, 0, stream>>>(
        ctxh + 512, 1024, dwq, dwq, 1 << 30, 512, qP, 512, 128, 512, 512, 64);
    dec_attn_k<<<1024, 128, 0, stream>>>(qP, dbq, xk, xv, dbuf);
    gemm_k<32, 64, 16, 2, 4><<<dim3(8, 4, 8), 256, 0, stream>>>(
        dbuf, 512, dwo, dwo, 1 << 30, 512, woP, 512, 128, 512, 512, 64);
    dec_ln_k<<<128, 256, 0, stream>>>(woP, dbo, dlng, dlnb, abuf);
    gemm_k<32, 64, 16, 2, 4><<<dim3(8, 4, 8), 256, 0, stream>>>(
        abuf, 512, dpw, dpw, 1 << 30, 512, pwP, 512, 128, 512, 512, 64);
    select_k<<<128, 256, 0, stream>>>(pwP, dpb, x, ew, ivis, ucount, complete, allvis,
                                      first, prev, ctxh, out, sbp, rpp, step);
  }
  final_k<<<1, 128, 0, stream>>>(complete, first, out);
}